// Round 4
// baseline (1719.948 us; speedup 1.0000x reference)
//
#include <hip/hip_runtime.h>
#include <hip/hip_bf16.h>
#include <stdint.h>

#define S_LEN 2048
#define HID 3584
#define NHEADS 28
#define KVHEADS 4
#define HD 128
#define QKV_N 4608
#define NREP 7
#define SCALE 0.08838834764831845f

typedef __attribute__((ext_vector_type(8))) short bf16x8;
typedef __attribute__((ext_vector_type(4))) float f32x4;

#define MFMA_B16(a, b, c) __builtin_amdgcn_mfma_f32_16x16x32_bf16((a), (b), (c), 0, 0, 0)

__device__ __forceinline__ void gl_lds16(const void* g, void* l) {
  __builtin_amdgcn_global_load_lds(
      (__attribute__((address_space(1))) void*)(void*)(g),
      (__attribute__((address_space(3))) void*)(l), 16, 0, 0);
}

__device__ __forceinline__ void split2(float x, __hip_bfloat16& h, __hip_bfloat16& l) {
  h = __float2bfloat16(x);
  l = __float2bfloat16(x - __bfloat162float(h));
}

// ---------------- fp32-in split-precision GEMM: C = A * B^T (+bias) ----------------
// B selected per col-block from {Bq (cols 0..3583), Bk (3584..4095), Bv (4096..4607)}.
template <bool HAS_BIAS>
__global__ __launch_bounds__(256, 2) void gemm_f32split(
    const float* __restrict__ A, int lda,
    const float* __restrict__ Bq, const float* __restrict__ Bk, const float* __restrict__ Bv,
    const float* __restrict__ bias, float* __restrict__ C, int ldc, int K) {
  __shared__ __hip_bfloat16 Ah[128 * 32], Al[128 * 32], Bh[128 * 32], Bl[128 * 32];
  const int tid = threadIdx.x;
  const int lane = tid & 63;
  const int wid = tid >> 6;
  const int wr = wid >> 1, wc = wid & 1;
  const int l15 = lane & 15, l4 = lane >> 4;
  const int bm = blockIdx.y * 128;
  const int bx = blockIdx.x;
  const float* Bp;
  int brow;
  if (bx < 28) { Bp = Bq; brow = bx * 128; }
  else if (bx < 32) { Bp = Bk; brow = (bx - 28) * 128; }
  else { Bp = Bv; brow = (bx - 32) * 128; }
  const int bn = bx * 128;
  f32x4 acc[4][4] = {};
  for (int k0 = 0; k0 < K; k0 += 32) {
    __syncthreads();
#pragma unroll
    for (int it = 0; it < 4; ++it) {
      int c = it * 256 + tid;
      int rw = c >> 3, cl = (c & 7) * 4;
      float4 va = *(const float4*)&A[(size_t)(bm + rw) * lda + k0 + cl];
      float4 vb = *(const float4*)&Bp[(size_t)(brow + rw) * lda + k0 + cl];
      __hip_bfloat16 ah[4], al[4], bh[4], bl[4];
      split2(va.x, ah[0], al[0]); split2(va.y, ah[1], al[1]);
      split2(va.z, ah[2], al[2]); split2(va.w, ah[3], al[3]);
      split2(vb.x, bh[0], bl[0]); split2(vb.y, bh[1], bl[1]);
      split2(vb.z, bh[2], bl[2]); split2(vb.w, bh[3], bl[3]);
      *(uint2*)&Ah[rw * 32 + cl] = *(const uint2*)ah;
      *(uint2*)&Al[rw * 32 + cl] = *(const uint2*)al;
      *(uint2*)&Bh[rw * 32 + cl] = *(const uint2*)bh;
      *(uint2*)&Bl[rw * 32 + cl] = *(const uint2*)bl;
    }
    __syncthreads();
    bf16x8 fah[4], fal[4], fbh[4], fbl[4];
#pragma unroll
    for (int m = 0; m < 4; ++m) {
      fah[m] = *(const bf16x8*)&Ah[(wr * 64 + m * 16 + l15) * 32 + l4 * 8];
      fal[m] = *(const bf16x8*)&Al[(wr * 64 + m * 16 + l15) * 32 + l4 * 8];
    }
#pragma unroll
    for (int n = 0; n < 4; ++n) {
      fbh[n] = *(const bf16x8*)&Bh[(wc * 64 + n * 16 + l15) * 32 + l4 * 8];
      fbl[n] = *(const bf16x8*)&Bl[(wc * 64 + n * 16 + l15) * 32 + l4 * 8];
    }
#pragma unroll
    for (int m = 0; m < 4; ++m)
#pragma unroll
      for (int n = 0; n < 4; ++n) {
        acc[m][n] = MFMA_B16(fah[m], fbh[n], acc[m][n]);
        acc[m][n] = MFMA_B16(fah[m], fbl[n], acc[m][n]);
        acc[m][n] = MFMA_B16(fal[m], fbh[n], acc[m][n]);
      }
  }
#pragma unroll
  for (int m = 0; m < 4; ++m)
#pragma unroll
    for (int n = 0; n < 4; ++n)
#pragma unroll
      for (int r = 0; r < 4; ++r) {
        size_t row = bm + wr * 64 + m * 16 + l4 * 4 + r;
        size_t col = bn + wc * 64 + n * 16 + l15;
        float v = acc[m][n][r];
        if (HAS_BIAS) v += bias[col];
        C[row * ldc + col] = v;
      }
}

// ---------------- rope on fp32 qkv, emit split bf16 Q/K ----------------
__global__ void rope_split(const float* __restrict__ qf, const float* __restrict__ cb,
                           const float* __restrict__ sb,
                           __hip_bfloat16* __restrict__ qhi, __hip_bfloat16* __restrict__ qlo,
                           __hip_bfloat16* __restrict__ khi, __hip_bfloat16* __restrict__ klo) {
  int idx = blockIdx.x * 256 + threadIdx.x;  // 2048 * 32 * 64
  int d1 = idx & 63;
  int hh = (idx >> 6) & 31;
  int s = idx >> 11;
  if (s >= S_LEN) return;
  const float* row = qf + (size_t)s * QKV_N + (hh < NHEADS ? hh * HD : HID + (hh - NHEADS) * HD);
  int d2 = d1 + 64;
  int ax1 = (d1 < 32) ? 0 : 1;  // sections: [0,32)->ax0, [32,80)->ax1, [80,128)->ax2
  int ax2 = (d2 < 80) ? 1 : 2;
  float c1 = cb[(size_t)ax1 * S_LEN * HD + (size_t)s * HD + d1];
  float s1 = sb[(size_t)ax1 * S_LEN * HD + (size_t)s * HD + d1];
  float c2 = cb[(size_t)ax2 * S_LEN * HD + (size_t)s * HD + d2];
  float s2 = sb[(size_t)ax2 * S_LEN * HD + (size_t)s * HD + d2];
  float x1 = row[d1], x2 = row[d2];
  float y1 = x1 * c1 - x2 * s1;
  float y2 = x2 * c2 + x1 * s2;
  __hip_bfloat16 *dh, *dl;
  size_t base;
  if (hh < NHEADS) { dh = qhi; dl = qlo; base = (size_t)s * HID + hh * HD; }
  else { dh = khi; dl = klo; base = (size_t)s * 512 + (hh - NHEADS) * HD; }
  __hip_bfloat16 h1, l1, h2, l2;
  split2(y1, h1, l1);
  split2(y2, h2, l2);
  dh[base + d1] = h1; dl[base + d1] = l1;
  dh[base + d2] = h2; dl[base + d2] = l2;
}

// ---------------- V transpose from fp32 qkv: vt[j][d][k] ----------------
__global__ void vtrans(const float* __restrict__ qf, __hip_bfloat16* __restrict__ vt) {
  __shared__ __hip_bfloat16 t[64][65];
  const int j = blockIdx.z;
  const int d0 = blockIdx.y * 64;
  const int k0 = blockIdx.x * 64;
  const int tid = threadIdx.x;
#pragma unroll
  for (int half = 0; half < 2; ++half) {
    int r = half * 32 + (tid >> 3);
    int c = (tid & 7) * 8;
    const float* p = qf + (size_t)(k0 + r) * QKV_N + (HID + 512) + j * HD + d0 + c;
    float4 a = ((const float4*)p)[0];
    float4 b = ((const float4*)p)[1];
    t[c + 0][r] = __float2bfloat16(a.x); t[c + 1][r] = __float2bfloat16(a.y);
    t[c + 2][r] = __float2bfloat16(a.z); t[c + 3][r] = __float2bfloat16(a.w);
    t[c + 4][r] = __float2bfloat16(b.x); t[c + 5][r] = __float2bfloat16(b.y);
    t[c + 6][r] = __float2bfloat16(b.z); t[c + 7][r] = __float2bfloat16(b.w);
  }
  __syncthreads();
#pragma unroll
  for (int half = 0; half < 2; ++half) {
    int r = half * 32 + (tid >> 3);
    int c = (tid & 7) * 8;
    __hip_bfloat16 tmp[8];
#pragma unroll
    for (int u = 0; u < 8; ++u) tmp[u] = t[r][c + u];
    *(bf16x8*)&vt[(size_t)j * (HD * S_LEN) + (size_t)(d0 + r) * S_LEN + k0 + c] = *(const bf16x8*)tmp;
  }
}

// ---------------- staging helpers ----------------
__device__ __forceinline__ void stage128(__hip_bfloat16* dst, const __hip_bfloat16* gsrc,
                                         int ldg, int tid) {
#pragma unroll
  for (int it = 0; it < 8; ++it) {
    int c = it * 256 + tid;
    int rw = c >> 4, cl = (c & 15) << 3;
    gl_lds16(gsrc + (size_t)rw * ldg + cl, dst + (size_t)(it * 256 + (tid & 192)) * 8);
  }
}
// 64 rows x 128 cols
__device__ __forceinline__ void stage64_128(__hip_bfloat16* dst, const __hip_bfloat16* gsrc,
                                            int ldg, int tid) {
#pragma unroll
  for (int it = 0; it < 4; ++it) {
    int c = it * 256 + tid;
    int rw = c >> 4, cl = (c & 15) << 3;
    gl_lds16(gsrc + (size_t)rw * ldg + cl, dst + (size_t)(it * 256 + (tid & 192)) * 8);
  }
}
// 128 rows x 64 cols
__device__ __forceinline__ void stage128_64(__hip_bfloat16* dst, const __hip_bfloat16* gsrc,
                                            int ldg, int tid) {
#pragma unroll
  for (int it = 0; it < 4; ++it) {
    int c = it * 256 + tid;
    int rw = c >> 3, cl = (c & 7) << 3;
    gl_lds16(gsrc + (size_t)rw * ldg + cl, dst + (size_t)(it * 256 + (tid & 192)) * 8);
  }
}

// split QK^T inner tile (128x128): acc += (qh+ql)·(kh+kl)^T (3-term)
__device__ __forceinline__ void qk_split_tile(const __hip_bfloat16* Qh, const __hip_bfloat16* Ql,
                                              const __hip_bfloat16* Kh, const __hip_bfloat16* Kl,
                                              int wid, int l15, int l4, f32x4 acc[2][8]) {
#pragma unroll
  for (int kk = 0; kk < 4; ++kk) {
    bf16x8 ah[2], al[2];
#pragma unroll
    for (int m = 0; m < 2; ++m) {
      ah[m] = *(const bf16x8*)&Qh[(wid * 32 + m * 16 + l15) * 128 + kk * 32 + l4 * 8];
      al[m] = *(const bf16x8*)&Ql[(wid * 32 + m * 16 + l15) * 128 + kk * 32 + l4 * 8];
    }
#pragma unroll
    for (int n = 0; n < 8; ++n) {
      bf16x8 bh = *(const bf16x8*)&Kh[(n * 16 + l15) * 128 + kk * 32 + l4 * 8];
      bf16x8 bl = *(const bf16x8*)&Kl[(n * 16 + l15) * 128 + kk * 32 + l4 * 8];
#pragma unroll
      for (int m = 0; m < 2; ++m) {
        acc[m][n] = MFMA_B16(ah[m], bh, acc[m][n]);
        acc[m][n] = MFMA_B16(ah[m], bl, acc[m][n]);
        acc[m][n] = MFMA_B16(al[m], bh, acc[m][n]);
      }
    }
  }
}

// ---------------- pass 1: row max + sumexp (split-precision logits) ----------------
__global__ __launch_bounds__(256, 1) void attn_stats(
    const __hip_bfloat16* __restrict__ qhi, const __hip_bfloat16* __restrict__ qlo,
    const __hip_bfloat16* __restrict__ khi, const __hip_bfloat16* __restrict__ klo,
    float* __restrict__ mbuf, float* __restrict__ lbuf) {
  __shared__ __hip_bfloat16 Qh[128 * 128];
  __shared__ __hip_bfloat16 Ql[128 * 128];
  __shared__ __hip_bfloat16 Kh[128 * 128];
  __shared__ __hip_bfloat16 Kl[128 * 128];
  const int qt = blockIdx.x, h = blockIdx.y;
  const int hkv = h / NREP;
  const int tid = threadIdx.x;
  const int lane = tid & 63, wid = tid >> 6;
  const int l15 = lane & 15, l4 = lane >> 4;
  stage128(Qh, qhi + (size_t)(qt * 128) * HID + h * HD, HID, tid);
  stage128(Ql, qlo + (size_t)(qt * 128) * HID + h * HD, HID, tid);
  float m_run[2][4], l_run[2][4];
#pragma unroll
  for (int m = 0; m < 2; ++m)
#pragma unroll
    for (int r = 0; r < 4; ++r) { m_run[m][r] = -1e30f; l_run[m][r] = 0.f; }
  for (int kt = 0; kt <= qt; ++kt) {
    __syncthreads();
    stage128(Kh, khi + (size_t)(kt * 128) * 512 + hkv * HD, 512, tid);
    stage128(Kl, klo + (size_t)(kt * 128) * 512 + hkv * HD, 512, tid);
    __syncthreads();
    f32x4 acc[2][8] = {};
    qk_split_tile(Qh, Ql, Kh, Kl, wid, l15, l4, acc);
    const bool diag = (kt == qt);
#pragma unroll
    for (int m = 0; m < 2; ++m)
#pragma unroll
      for (int r = 0; r < 4; ++r) {
        int rowl = wid * 32 + m * 16 + l4 * 4 + r;
        float v[8];
        float tmax = -1e30f;
#pragma unroll
        for (int n = 0; n < 8; ++n) {
          float x = acc[m][n][r] * SCALE;
          if (diag && (n * 16 + l15) > rowl) x = -1e30f;
          v[n] = x;
          tmax = fmaxf(tmax, x);
        }
        tmax = fmaxf(tmax, __shfl_xor(tmax, 1));
        tmax = fmaxf(tmax, __shfl_xor(tmax, 2));
        tmax = fmaxf(tmax, __shfl_xor(tmax, 4));
        tmax = fmaxf(tmax, __shfl_xor(tmax, 8));
        float mold = m_run[m][r];
        float mnew = fmaxf(mold, tmax);
        float sum = 0.f;
#pragma unroll
        for (int n = 0; n < 8; ++n) sum += __expf(v[n] - mnew);
        sum += __shfl_xor(sum, 1);
        sum += __shfl_xor(sum, 2);
        sum += __shfl_xor(sum, 4);
        sum += __shfl_xor(sum, 8);
        l_run[m][r] = l_run[m][r] * __expf(mold - mnew) + sum;
        m_run[m][r] = mnew;
      }
  }
  if (l15 == 0) {
#pragma unroll
    for (int m = 0; m < 2; ++m)
#pragma unroll
      for (int r = 0; r < 4; ++r) {
        int row = qt * 128 + wid * 32 + m * 16 + l4 * 4 + r;
        mbuf[h * S_LEN + row] = m_run[m][r];
        lbuf[h * S_LEN + row] = l_run[m][r];
      }
  }
}

// ---------------- pass 2: per-key accumulated softmax mass (split logits) ----------------
__global__ __launch_bounds__(256, 1) void attn_scores(
    const __hip_bfloat16* __restrict__ qhi, const __hip_bfloat16* __restrict__ qlo,
    const __hip_bfloat16* __restrict__ khi, const __hip_bfloat16* __restrict__ klo,
    const float* __restrict__ mbuf, const float* __restrict__ lbuf,
    float* __restrict__ scores) {
  __shared__ __hip_bfloat16 Qh[128 * 128];
  __shared__ __hip_bfloat16 Ql[128 * 128];
  __shared__ __hip_bfloat16 Kh[128 * 128];
  __shared__ __hip_bfloat16 Kl[128 * 128];
  const int qt = blockIdx.x, h = blockIdx.y;
  const int hkv = h / NREP;
  const int tid = threadIdx.x;
  const int lane = tid & 63, wid = tid >> 6;
  const int l15 = lane & 15, l4 = lane >> 4;
  stage128(Qh, qhi + (size_t)(qt * 128) * HID + h * HD, HID, tid);
  stage128(Ql, qlo + (size_t)(qt * 128) * HID + h * HD, HID, tid);
  float mrow[2][4], invl[2][4];
#pragma unroll
  for (int m = 0; m < 2; ++m)
#pragma unroll
    for (int r = 0; r < 4; ++r) {
      int row = qt * 128 + wid * 32 + m * 16 + l4 * 4 + r;
      mrow[m][r] = mbuf[h * S_LEN + row];
      invl[m][r] = 1.0f / lbuf[h * S_LEN + row];
    }
  for (int kt = 0; kt <= qt; ++kt) {
    __syncthreads();
    stage128(Kh, khi + (size_t)(kt * 128) * 512 + hkv * HD, 512, tid);
    stage128(Kl, klo + (size_t)(kt * 128) * 512 + hkv * HD, 512, tid);
    __syncthreads();
    f32x4 acc[2][8] = {};
    qk_split_tile(Qh, Ql, Kh, Kl, wid, l15, l4, acc);
    const bool diag = (kt == qt);
    float colsum[8];
#pragma unroll
    for (int n = 0; n < 8; ++n) colsum[n] = 0.f;
#pragma unroll
    for (int m = 0; m < 2; ++m)
#pragma unroll
      for (int r = 0; r < 4; ++r) {
        int rowl = wid * 32 + m * 16 + l4 * 4 + r;
#pragma unroll
        for (int n = 0; n < 8; ++n) {
          float x = acc[m][n][r] * SCALE;
          float wv = 0.f;
          if (!(diag && (n * 16 + l15) > rowl))
            wv = __expf(x - mrow[m][r]) * invl[m][r];
          colsum[n] += wv;
        }
      }
#pragma unroll
    for (int n = 0; n < 8; ++n) {
      colsum[n] += __shfl_xor(colsum[n], 16);
      colsum[n] += __shfl_xor(colsum[n], 32);
    }
    if (lane < 16) {
#pragma unroll
      for (int n = 0; n < 8; ++n)
        atomicAdd(&scores[h * S_LEN + kt * 128 + n * 16 + lane], colsum[n]);
    }
  }
}

// ---------------- pass 3: exact top-k (boundary search) -> keep mask ----------------
__global__ void h2o_topk(const float* __restrict__ scores, unsigned char* __restrict__ keep) {
  const int h = blockIdx.x;
  const int tid = threadIdx.x;
  const int MS = 409, ME = 1844, REGN = 1435, KSEL = 204;
  __shared__ float sv[1435];
  __shared__ int cnt, eqn;
  __shared__ int eqlist[256];
  for (int i = tid; i < REGN; i += 256) sv[i] = scores[h * S_LEN + MS + i];
  for (int i = tid; i < S_LEN; i += 256)
    keep[h * S_LEN + i] = (i < MS || i >= ME) ? 1 : 0;
  __syncthreads();
  unsigned lo = 0u, hi = 0x7f800000u;
  while (hi - lo > 1u) {
    unsigned mid = lo + ((hi - lo) >> 1);
    if (tid == 0) cnt = 0;
    __syncthreads();
    int lc = 0;
    for (int i = tid; i < REGN; i += 256) lc += (__float_as_uint(sv[i]) >= mid) ? 1 : 0;
    if (lc) atomicAdd(&cnt, lc);
    __syncthreads();
    int c = cnt;
    __syncthreads();
    if (c >= KSEL) lo = mid;
    else hi = mid;
  }
  if (tid == 0) { cnt = 0; eqn = 0; }
  __syncthreads();
  int lgt = 0;
  for (int i = tid; i < REGN; i += 256) {
    unsigned b = __float_as_uint(sv[i]);
    if (b > lo) { keep[h * S_LEN + MS + i] = 1; lgt++; }
    else if (b == lo) {
      int p = atomicAdd(&eqn, 1);
      if (p < 256) eqlist[p] = i;
    }
  }
  if (lgt) atomicAdd(&cnt, lgt);
  __syncthreads();
  if (tid == 0) {
    int r = KSEL - cnt;
    int ne = eqn > 256 ? 256 : eqn;
    for (int t = 0; t < r; ++t) {
      int best = 0x7fffffff, bj = -1;
      for (int j = 0; j < ne; ++j)
        if (eqlist[j] < best) { best = eqlist[j]; bj = j; }
      if (bj < 0) break;
      keep[h * S_LEN + MS + best] = 1;
      eqlist[bj] = 0x7fffffff;
    }
  }
}

// ---------------- pass 4: pruned+renormalized attention output (split QK, fp32 ctx) ----------------
__global__ __launch_bounds__(256, 1) void attn_out(
    const __hip_bfloat16* __restrict__ qhi, const __hip_bfloat16* __restrict__ qlo,
    const __hip_bfloat16* __restrict__ khi, const __hip_bfloat16* __restrict__ klo,
    const __hip_bfloat16* __restrict__ vt, const float* __restrict__ mbuf,
    const unsigned char* __restrict__ keep, float* __restrict__ ctx) {
  __shared__ __hip_bfloat16 Qh[128 * 128];   // 32 KB
  __shared__ __hip_bfloat16 Ql[128 * 128];   // 32 KB
  __shared__ __hip_bfloat16 Kh[64 * 128];    // 16 KB
  __shared__ __hip_bfloat16 Kl[64 * 128];    // 16 KB
  __shared__ __hip_bfloat16 Vtl[128 * 64];   // 16 KB
  __shared__ __hip_bfloat16 Wt[128 * 64];    // 16 KB -> 128 KB total
  const int qt = blockIdx.x, h = blockIdx.y;
  const int hkv = h / NREP;
  const int tid = threadIdx.x;
  const int lane = tid & 63, wid = tid >> 6;
  const int l15 = lane & 15, l4 = lane >> 4;
  stage128(Qh, qhi + (size_t)(qt * 128) * HID + h * HD, HID, tid);
  stage128(Ql, qlo + (size_t)(qt * 128) * HID + h * HD, HID, tid);
  float mrow[2][4];
#pragma unroll
  for (int m = 0; m < 2; ++m)
#pragma unroll
    for (int r = 0; r < 4; ++r) {
      int row = qt * 128 + wid * 32 + m * 16 + l4 * 4 + r;
      mrow[m][r] = mbuf[h * S_LEN + row];
    }
  f32x4 o[2][8] = {};
  float dens[2][4] = {};
  const int nkt = 2 * qt + 2;  // 64-wide K blocks
  for (int kt = 0; kt < nkt; ++kt) {
    __syncthreads();
    stage64_128(Kh, khi + (size_t)(kt * 64) * 512 + hkv * HD, 512, tid);
    stage64_128(Kl, klo + (size_t)(kt * 64) * 512 + hkv * HD, 512, tid);
    stage128_64(Vtl, vt + (size_t)hkv * (HD * S_LEN) + kt * 64, S_LEN, tid);
    __syncthreads();
    // QK^T 3-term over 64 keys
    f32x4 acc[2][4] = {};
#pragma unroll
    for (int kk = 0; kk < 4; ++kk) {
      bf16x8 ah[2], al[2];
#pragma unroll
      for (int m = 0; m < 2; ++m) {
        ah[m] = *(const bf16x8*)&Qh[(wid * 32 + m * 16 + l15) * 128 + kk * 32 + l4 * 8];
        al[m] = *(const bf16x8*)&Ql[(wid * 32 + m * 16 + l15) * 128 + kk * 32 + l4 * 8];
      }
#pragma unroll
      for (int n = 0; n < 4; ++n) {
        bf16x8 bh = *(const bf16x8*)&Kh[(n * 16 + l15) * 128 + kk * 32 + l4 * 8];
        bf16x8 bl = *(const bf16x8*)&Kl[(n * 16 + l15) * 128 + kk * 32 + l4 * 8];
#pragma unroll
        for (int m = 0; m < 2; ++m) {
          acc[m][n] = MFMA_B16(ah[m], bh, acc[m][n]);
          acc[m][n] = MFMA_B16(ah[m], bl, acc[m][n]);
          acc[m][n] = MFMA_B16(al[m], bh, acc[m][n]);
        }
      }
    }
    // weights + Wt (each wave writes/reads only its own 32 rows)
#pragma unroll
    for (int m = 0; m < 2; ++m)
#pragma unroll
      for (int r = 0; r < 4; ++r) {
        int rowg = qt * 128 + wid * 32 + m * 16 + l4 * 4 + r;
        int rowl = wid * 32 + m * 16 + l4 * 4 + r;
#pragma unroll
        for (int n = 0; n < 4; ++n) {
          int coll = n * 16 + l15;
          int colg = kt * 64 + coll;
          float wv = 0.f;
          if (colg <= rowg) {
            float kf = (float)keep[h * S_LEN + colg];
            wv = kf * __expf(acc[m][n][r] * SCALE - mrow[m][r]);
          }
          dens[m][r] += wv;
          Wt[rowl * 64 + coll] = __float2bfloat16(wv);
        }
      }
    // PV: o[row][d] += W[row][k] * Vt[d][k]
#pragma unroll
    for (int kk = 0; kk < 2; ++kk) {
      bf16x8 af[2];
#pragma unroll
      for (int m = 0; m < 2; ++m)
        af[m] = *(const bf16x8*)&Wt[(wid * 32 + m * 16 + l15) * 64 + kk * 32 + l4 * 8];
#pragma unroll
      for (int n = 0; n < 8; ++n) {
        bf16x8 bf = *(const bf16x8*)&Vtl[(n * 16 + l15) * 64 + kk * 32 + l4 * 8];
#pragma unroll
        for (int m = 0; m < 2; ++m)
          o[m][n] = MFMA_B16(af[m], bf, o[m][n]);
      }
    }
  }
  float invd[2][4];
#pragma unroll
  for (int m = 0; m < 2; ++m)
#pragma unroll
    for (int r = 0; r < 4; ++r) {
      float d = dens[m][r];
      d += __shfl_xor(d, 1);
      d += __shfl_xor(d, 2);
      d += __shfl_xor(d, 4);
      d += __shfl_xor(d, 8);
      invd[m][r] = 1.0f / fmaxf(d, 1e-20f);
    }
#pragma unroll
  for (int m = 0; m < 2; ++m)
#pragma unroll
    for (int n = 0; n < 8; ++n)
#pragma unroll
      for (int r = 0; r < 4; ++r) {
        size_t row = qt * 128 + wid * 32 + m * 16 + l4 * 4 + r;
        size_t col = h * HD + n * 16 + l15;
        ctx[row * HID + col] = o[m][n][r] * invd[m][r];
      }
}

// ---------------- host glue ----------------
extern "C" void kernel_launch(void* const* d_in, const int* in_sizes, int n_in,
                              void* d_out, int out_size, void* d_ws, size_t ws_size,
                              hipStream_t stream) {
  const float* hidden = (const float*)d_in[0];
  const float* cosb = (const float*)d_in[2];
  const float* sinb = (const float*)d_in[3];
  const float* q_w = (const float*)d_in[4];
  const float* q_b = (const float*)d_in[5];
  const float* k_w = (const float*)d_in[6];
  const float* k_b = (const float*)d_in[7];
  const float* v_w = (const float*)d_in[8];
  const float* v_b = (const float*)d_in[9];
  const float* o_w = (const float*)d_in[10];

  char* ws = (char*)d_ws;
  float* qkv_f32 = (float*)(ws + 0);                       // 37,748,736
  float* ctx_f32 = (float*)(ws + 0);                       // 29,360,128 (overlays dead qkv_f32)
  __hip_bfloat16* qhi = (__hip_bfloat16*)(ws + 37748736);  // 14,680,064
  __hip_bfloat16* qlo = (__hip_bfloat16*)(ws + 52428800);  // 14,680,064
  __hip_bfloat16* khi = (__hip_bfloat16*)(ws + 67108864);  //  2,097,152
  __hip_bfloat16* klo = (__hip_bfloat16*)(ws + 69206016);  //  2,097,152
  __hip_bfloat16* vt = (__hip_bfloat16*)(ws + 71303168);   //  2,097,152
  float* mbuf = (float*)(ws + 73400320);                   //    229,376
  float* lbuf = (float*)(ws + 73629696);                   //    229,376
  float* scores = (float*)(ws + 73859072);                 //    229,376
  unsigned char* keep = (unsigned char*)(ws + 74088448);   //     57,344
  float* biasb = (float*)(ws + 74145792);                  //     18,432 -> 74,164,224 total

  hipMemcpyAsync(biasb, q_b, 3584 * 4, hipMemcpyDeviceToDevice, stream);
  hipMemcpyAsync(biasb + 3584, k_b, 512 * 4, hipMemcpyDeviceToDevice, stream);
  hipMemcpyAsync(biasb + 4096, v_b, 512 * 4, hipMemcpyDeviceToDevice, stream);
  hipMemsetAsync(scores, 0, NHEADS * S_LEN * 4, stream);

  // QKV projection, fp32-grade via split GEMM (+bias)
  gemm_f32split<true><<<dim3(36, 16), 256, 0, stream>>>(
      hidden, HID, q_w, k_w, v_w, biasb, qkv_f32, QKV_N, HID);

  rope_split<<<16384, 256, 0, stream>>>(qkv_f32, cosb, sinb, qhi, qlo, khi, klo);
  vtrans<<<dim3(32, 2, 4), 256, 0, stream>>>(qkv_f32, vt);

  attn_stats<<<dim3(16, 28), 256, 0, stream>>>(qhi, qlo, khi, klo, mbuf, lbuf);
  attn_scores<<<dim3(16, 28), 256, 0, stream>>>(qhi, qlo, khi, klo, mbuf, lbuf, scores);
  h2o_topk<<<28, 256, 0, stream>>>(scores, keep);
  attn_out<<<dim3(16, 28), 256, 0, stream>>>(qhi, qlo, khi, klo, vt, mbuf, keep, ctx_f32);

  // output projection, fp32-grade split GEMM
  gemm_f32split<false><<<dim3(28, 16), 256, 0, stream>>>(
      ctx_f32, HID, o_w, nullptr, nullptr, nullptr, (float*)d_out, HID, HID);
}

// Round 5
// 1293.301 us; speedup vs baseline: 1.3299x; 1.3299x over previous
//
#include <hip/hip_runtime.h>
#include <hip/hip_bf16.h>
#include <stdint.h>

#define S_LEN 2048
#define HID 3584
#define NHEADS 28
#define KVHEADS 4
#define HD 128
#define QKV_N 4608
#define NREP 7
#define SCALE 0.08838834764831845f

typedef __attribute__((ext_vector_type(8))) short bf16x8;
typedef __attribute__((ext_vector_type(4))) float f32x4;

#define MFMA_B16(a, b, c) __builtin_amdgcn_mfma_f32_16x16x32_bf16((a), (b), (c), 0, 0, 0)

__device__ __forceinline__ void gl_lds16(const void* g, void* l) {
  __builtin_amdgcn_global_load_lds(
      (__attribute__((address_space(1))) void*)(void*)(g),
      (__attribute__((address_space(3))) void*)(l), 16, 0, 0);
}

__device__ __forceinline__ void split2(float x, __hip_bfloat16& h, __hip_bfloat16& l) {
  h = __float2bfloat16(x);
  l = __float2bfloat16(x - __bfloat162float(h));
}

// ---------------- fp32 -> (hi, lo) bf16 split ----------------
__global__ void split_f32_bf16(const float* __restrict__ src, __hip_bfloat16* __restrict__ hi,
                               __hip_bfloat16* __restrict__ lo, int n4) {
  int i = blockIdx.x * 256 + threadIdx.x;
  if (i >= n4) return;
  float4 v = ((const float4*)src)[i];
  __hip_bfloat16 th[4], tl[4];
  float x[4] = {v.x, v.y, v.z, v.w};
#pragma unroll
  for (int u = 0; u < 4; ++u) split2(x[u], th[u], tl[u]);
  ((uint2*)hi)[i] = *(const uint2*)th;
  ((uint2*)lo)[i] = *(const uint2*)tl;
}

// ---------------- pre-split 3-term GEMM: C = (Ah+Al)*(Bh+Bl)^T (+bias) ----------------
// m97-structure: global_load_lds width-16 staging of all four tiles, BK=32.
template <bool HAS_BIAS>
__global__ __launch_bounds__(256, 2) void gemm3t(
    const __hip_bfloat16* __restrict__ Ahg, const __hip_bfloat16* __restrict__ Alg, int lda,
    const __hip_bfloat16* __restrict__ Bhg, const __hip_bfloat16* __restrict__ Blg, int ldb,
    const float* __restrict__ bias, float* __restrict__ C, int ldc, int K) {
  __shared__ __hip_bfloat16 lAh[128 * 32], lAl[128 * 32], lBh[128 * 32], lBl[128 * 32];
  const int tid = threadIdx.x;
  const int lane = tid & 63;
  const int wid = tid >> 6;
  const int wr = wid >> 1, wc = wid & 1;
  const int l15 = lane & 15, l4 = lane >> 4;
  const int bm = blockIdx.y * 128, bn = blockIdx.x * 128;
  f32x4 acc[4][4] = {};
  for (int k0 = 0; k0 < K; k0 += 32) {
    __syncthreads();
#pragma unroll
    for (int it = 0; it < 2; ++it) {
      int c = it * 256 + tid;
      int row = c >> 2, col = (c & 3) << 3;
      int lo = (it * 256 + (tid & 192)) * 8;
      gl_lds16(Ahg + (size_t)(bm + row) * lda + (k0 + col), &lAh[lo]);
      gl_lds16(Alg + (size_t)(bm + row) * lda + (k0 + col), &lAl[lo]);
      gl_lds16(Bhg + (size_t)(bn + row) * ldb + (k0 + col), &lBh[lo]);
      gl_lds16(Blg + (size_t)(bn + row) * ldb + (k0 + col), &lBl[lo]);
    }
    __syncthreads();
    bf16x8 ah[4], al[4], bh[4], bl[4];
#pragma unroll
    for (int m = 0; m < 4; ++m) {
      ah[m] = *(const bf16x8*)&lAh[(wr * 64 + m * 16 + l15) * 32 + l4 * 8];
      al[m] = *(const bf16x8*)&lAl[(wr * 64 + m * 16 + l15) * 32 + l4 * 8];
    }
#pragma unroll
    for (int n = 0; n < 4; ++n) {
      bh[n] = *(const bf16x8*)&lBh[(wc * 64 + n * 16 + l15) * 32 + l4 * 8];
      bl[n] = *(const bf16x8*)&lBl[(wc * 64 + n * 16 + l15) * 32 + l4 * 8];
    }
#pragma unroll
    for (int m = 0; m < 4; ++m)
#pragma unroll
      for (int n = 0; n < 4; ++n) {
        acc[m][n] = MFMA_B16(ah[m], bh[n], acc[m][n]);
        acc[m][n] = MFMA_B16(ah[m], bl[n], acc[m][n]);
        acc[m][n] = MFMA_B16(al[m], bh[n], acc[m][n]);
      }
  }
#pragma unroll
  for (int m = 0; m < 4; ++m)
#pragma unroll
    for (int n = 0; n < 4; ++n)
#pragma unroll
      for (int r = 0; r < 4; ++r) {
        size_t row = bm + wr * 64 + m * 16 + l4 * 4 + r;
        size_t col = bn + wc * 64 + n * 16 + l15;
        float v = acc[m][n][r];
        if (HAS_BIAS) v += bias[col];
        C[row * ldc + col] = v;
      }
}

// ---------------- rope on fp32 qkv, emit split bf16 Q/K ----------------
__global__ void rope_split(const float* __restrict__ qf, const float* __restrict__ cb,
                           const float* __restrict__ sb,
                           __hip_bfloat16* __restrict__ qhi, __hip_bfloat16* __restrict__ qlo,
                           __hip_bfloat16* __restrict__ khi, __hip_bfloat16* __restrict__ klo) {
  int idx = blockIdx.x * 256 + threadIdx.x;  // 2048 * 32 * 64
  int d1 = idx & 63;
  int hh = (idx >> 6) & 31;
  int s = idx >> 11;
  if (s >= S_LEN) return;
  const float* row = qf + (size_t)s * QKV_N + (hh < NHEADS ? hh * HD : HID + (hh - NHEADS) * HD);
  int d2 = d1 + 64;
  int ax1 = (d1 < 32) ? 0 : 1;  // sections: [0,32)->ax0, [32,80)->ax1, [80,128)->ax2
  int ax2 = (d2 < 80) ? 1 : 2;
  float c1 = cb[(size_t)ax1 * S_LEN * HD + (size_t)s * HD + d1];
  float s1 = sb[(size_t)ax1 * S_LEN * HD + (size_t)s * HD + d1];
  float c2 = cb[(size_t)ax2 * S_LEN * HD + (size_t)s * HD + d2];
  float s2 = sb[(size_t)ax2 * S_LEN * HD + (size_t)s * HD + d2];
  float x1 = row[d1], x2 = row[d2];
  float y1 = x1 * c1 - x2 * s1;
  float y2 = x2 * c2 + x1 * s2;
  __hip_bfloat16 *dh, *dl;
  size_t base;
  if (hh < NHEADS) { dh = qhi; dl = qlo; base = (size_t)s * HID + hh * HD; }
  else { dh = khi; dl = klo; base = (size_t)s * 512 + (hh - NHEADS) * HD; }
  __hip_bfloat16 h1, l1, h2, l2;
  split2(y1, h1, l1);
  split2(y2, h2, l2);
  dh[base + d1] = h1; dl[base + d1] = l1;
  dh[base + d2] = h2; dl[base + d2] = l2;
}

// ---------------- V transpose from fp32 qkv: vt[j][d][k] ----------------
__global__ void vtrans(const float* __restrict__ qf, __hip_bfloat16* __restrict__ vt) {
  __shared__ __hip_bfloat16 t[64][65];
  const int j = blockIdx.z;
  const int d0 = blockIdx.y * 64;
  const int k0 = blockIdx.x * 64;
  const int tid = threadIdx.x;
#pragma unroll
  for (int half = 0; half < 2; ++half) {
    int r = half * 32 + (tid >> 3);
    int c = (tid & 7) * 8;
    const float* p = qf + (size_t)(k0 + r) * QKV_N + (HID + 512) + j * HD + d0 + c;
    float4 a = ((const float4*)p)[0];
    float4 b = ((const float4*)p)[1];
    t[c + 0][r] = __float2bfloat16(a.x); t[c + 1][r] = __float2bfloat16(a.y);
    t[c + 2][r] = __float2bfloat16(a.z); t[c + 3][r] = __float2bfloat16(a.w);
    t[c + 4][r] = __float2bfloat16(b.x); t[c + 5][r] = __float2bfloat16(b.y);
    t[c + 6][r] = __float2bfloat16(b.z); t[c + 7][r] = __float2bfloat16(b.w);
  }
  __syncthreads();
#pragma unroll
  for (int half = 0; half < 2; ++half) {
    int r = half * 32 + (tid >> 3);
    int c = (tid & 7) * 8;
    __hip_bfloat16 tmp[8];
#pragma unroll
    for (int u = 0; u < 8; ++u) tmp[u] = t[r][c + u];
    *(bf16x8*)&vt[(size_t)j * (HD * S_LEN) + (size_t)(d0 + r) * S_LEN + k0 + c] = *(const bf16x8*)tmp;
  }
}

// ---------------- staging helpers ----------------
__device__ __forceinline__ void stage128(__hip_bfloat16* dst, const __hip_bfloat16* gsrc,
                                         int ldg, int tid) {
#pragma unroll
  for (int it = 0; it < 8; ++it) {
    int c = it * 256 + tid;
    int rw = c >> 4, cl = (c & 15) << 3;
    gl_lds16(gsrc + (size_t)rw * ldg + cl, dst + (size_t)(it * 256 + (tid & 192)) * 8);
  }
}
// 64 rows x 128 cols
__device__ __forceinline__ void stage64_128(__hip_bfloat16* dst, const __hip_bfloat16* gsrc,
                                            int ldg, int tid) {
#pragma unroll
  for (int it = 0; it < 4; ++it) {
    int c = it * 256 + tid;
    int rw = c >> 4, cl = (c & 15) << 3;
    gl_lds16(gsrc + (size_t)rw * ldg + cl, dst + (size_t)(it * 256 + (tid & 192)) * 8);
  }
}
// 128 rows x 64 cols
__device__ __forceinline__ void stage128_64(__hip_bfloat16* dst, const __hip_bfloat16* gsrc,
                                            int ldg, int tid) {
#pragma unroll
  for (int it = 0; it < 4; ++it) {
    int c = it * 256 + tid;
    int rw = c >> 3, cl = (c & 7) << 3;
    gl_lds16(gsrc + (size_t)rw * ldg + cl, dst + (size_t)(it * 256 + (tid & 192)) * 8);
  }
}

// split QK^T inner tile (128x128): acc += (qh+ql)·(kh+kl)^T (3-term)
__device__ __forceinline__ void qk_split_tile(const __hip_bfloat16* Qh, const __hip_bfloat16* Ql,
                                              const __hip_bfloat16* Kh, const __hip_bfloat16* Kl,
                                              int wid, int l15, int l4, f32x4 acc[2][8]) {
#pragma unroll
  for (int kk = 0; kk < 4; ++kk) {
    bf16x8 ah[2], al[2];
#pragma unroll
    for (int m = 0; m < 2; ++m) {
      ah[m] = *(const bf16x8*)&Qh[(wid * 32 + m * 16 + l15) * 128 + kk * 32 + l4 * 8];
      al[m] = *(const bf16x8*)&Ql[(wid * 32 + m * 16 + l15) * 128 + kk * 32 + l4 * 8];
    }
#pragma unroll
    for (int n = 0; n < 8; ++n) {
      bf16x8 bh = *(const bf16x8*)&Kh[(n * 16 + l15) * 128 + kk * 32 + l4 * 8];
      bf16x8 bl = *(const bf16x8*)&Kl[(n * 16 + l15) * 128 + kk * 32 + l4 * 8];
#pragma unroll
      for (int m = 0; m < 2; ++m) {
        acc[m][n] = MFMA_B16(ah[m], bh, acc[m][n]);
        acc[m][n] = MFMA_B16(ah[m], bl, acc[m][n]);
        acc[m][n] = MFMA_B16(al[m], bh, acc[m][n]);
      }
    }
  }
}

// ---------------- pass 1: row max + sumexp, 1-term (hi-only) logits ----------------
// l enters only as the per-row score scale; ~0.1% error is ranking noise.
__global__ __launch_bounds__(256, 2) void attn_stats_lite(
    const __hip_bfloat16* __restrict__ qhi, const __hip_bfloat16* __restrict__ khi,
    float* __restrict__ mbuf, float* __restrict__ lbuf) {
  __shared__ __hip_bfloat16 Qh[128 * 128];
  __shared__ __hip_bfloat16 Kh[128 * 128];
  const int qt = blockIdx.x, h = blockIdx.y;
  const int hkv = h / NREP;
  const int tid = threadIdx.x;
  const int lane = tid & 63, wid = tid >> 6;
  const int l15 = lane & 15, l4 = lane >> 4;
  stage128(Qh, qhi + (size_t)(qt * 128) * HID + h * HD, HID, tid);
  float m_run[2][4], l_run[2][4];
#pragma unroll
  for (int m = 0; m < 2; ++m)
#pragma unroll
    for (int r = 0; r < 4; ++r) { m_run[m][r] = -1e30f; l_run[m][r] = 0.f; }
  for (int kt = 0; kt <= qt; ++kt) {
    __syncthreads();
    stage128(Kh, khi + (size_t)(kt * 128) * 512 + hkv * HD, 512, tid);
    __syncthreads();
    f32x4 acc[2][8] = {};
#pragma unroll
    for (int kk = 0; kk < 4; ++kk) {
      bf16x8 ah[2];
#pragma unroll
      for (int m = 0; m < 2; ++m)
        ah[m] = *(const bf16x8*)&Qh[(wid * 32 + m * 16 + l15) * 128 + kk * 32 + l4 * 8];
#pragma unroll
      for (int n = 0; n < 8; ++n) {
        bf16x8 bh = *(const bf16x8*)&Kh[(n * 16 + l15) * 128 + kk * 32 + l4 * 8];
#pragma unroll
        for (int m = 0; m < 2; ++m)
          acc[m][n] = MFMA_B16(ah[m], bh, acc[m][n]);
      }
    }
    const bool diag = (kt == qt);
#pragma unroll
    for (int m = 0; m < 2; ++m)
#pragma unroll
      for (int r = 0; r < 4; ++r) {
        int rowl = wid * 32 + m * 16 + l4 * 4 + r;
        float v[8];
        float tmax = -1e30f;
#pragma unroll
        for (int n = 0; n < 8; ++n) {
          float x = acc[m][n][r] * SCALE;
          if (diag && (n * 16 + l15) > rowl) x = -1e30f;
          v[n] = x;
          tmax = fmaxf(tmax, x);
        }
        tmax = fmaxf(tmax, __shfl_xor(tmax, 1));
        tmax = fmaxf(tmax, __shfl_xor(tmax, 2));
        tmax = fmaxf(tmax, __shfl_xor(tmax, 4));
        tmax = fmaxf(tmax, __shfl_xor(tmax, 8));
        float mold = m_run[m][r];
        float mnew = fmaxf(mold, tmax);
        float sum = 0.f;
#pragma unroll
        for (int n = 0; n < 8; ++n) sum += __expf(v[n] - mnew);
        sum += __shfl_xor(sum, 1);
        sum += __shfl_xor(sum, 2);
        sum += __shfl_xor(sum, 4);
        sum += __shfl_xor(sum, 8);
        l_run[m][r] = l_run[m][r] * __expf(mold - mnew) + sum;
        m_run[m][r] = mnew;
      }
  }
  if (l15 == 0) {
#pragma unroll
    for (int m = 0; m < 2; ++m)
#pragma unroll
      for (int r = 0; r < 4; ++r) {
        int row = qt * 128 + wid * 32 + m * 16 + l4 * 4 + r;
        mbuf[h * S_LEN + row] = m_run[m][r];
        lbuf[h * S_LEN + row] = l_run[m][r];
      }
  }
}

// ---------------- pass 2: per-key accumulated softmax mass (split logits) ----------------
__global__ __launch_bounds__(256, 1) void attn_scores(
    const __hip_bfloat16* __restrict__ qhi, const __hip_bfloat16* __restrict__ qlo,
    const __hip_bfloat16* __restrict__ khi, const __hip_bfloat16* __restrict__ klo,
    const float* __restrict__ mbuf, const float* __restrict__ lbuf,
    float* __restrict__ scores) {
  __shared__ __hip_bfloat16 Qh[128 * 128];
  __shared__ __hip_bfloat16 Ql[128 * 128];
  __shared__ __hip_bfloat16 Kh[128 * 128];
  __shared__ __hip_bfloat16 Kl[128 * 128];
  const int qt = blockIdx.x, h = blockIdx.y;
  const int hkv = h / NREP;
  const int tid = threadIdx.x;
  const int lane = tid & 63, wid = tid >> 6;
  const int l15 = lane & 15, l4 = lane >> 4;
  stage128(Qh, qhi + (size_t)(qt * 128) * HID + h * HD, HID, tid);
  stage128(Ql, qlo + (size_t)(qt * 128) * HID + h * HD, HID, tid);
  float mrow[2][4], invl[2][4];
#pragma unroll
  for (int m = 0; m < 2; ++m)
#pragma unroll
    for (int r = 0; r < 4; ++r) {
      int row = qt * 128 + wid * 32 + m * 16 + l4 * 4 + r;
      mrow[m][r] = mbuf[h * S_LEN + row];
      invl[m][r] = 1.0f / lbuf[h * S_LEN + row];
    }
  for (int kt = 0; kt <= qt; ++kt) {
    __syncthreads();
    stage128(Kh, khi + (size_t)(kt * 128) * 512 + hkv * HD, 512, tid);
    stage128(Kl, klo + (size_t)(kt * 128) * 512 + hkv * HD, 512, tid);
    __syncthreads();
    f32x4 acc[2][8] = {};
    qk_split_tile(Qh, Ql, Kh, Kl, wid, l15, l4, acc);
    const bool diag = (kt == qt);
    float colsum[8];
#pragma unroll
    for (int n = 0; n < 8; ++n) colsum[n] = 0.f;
#pragma unroll
    for (int m = 0; m < 2; ++m)
#pragma unroll
      for (int r = 0; r < 4; ++r) {
        int rowl = wid * 32 + m * 16 + l4 * 4 + r;
#pragma unroll
        for (int n = 0; n < 8; ++n) {
          float x = acc[m][n][r] * SCALE;
          float wv = 0.f;
          if (!(diag && (n * 16 + l15) > rowl))
            wv = __expf(x - mrow[m][r]) * invl[m][r];
          colsum[n] += wv;
        }
      }
#pragma unroll
    for (int n = 0; n < 8; ++n) {
      colsum[n] += __shfl_xor(colsum[n], 16);
      colsum[n] += __shfl_xor(colsum[n], 32);
    }
    if (lane < 16) {
#pragma unroll
      for (int n = 0; n < 8; ++n)
        atomicAdd(&scores[h * S_LEN + kt * 128 + n * 16 + lane], colsum[n]);
    }
  }
}

// ---------------- pass 3: exact top-k (boundary search) -> keep mask ----------------
__global__ void h2o_topk(const float* __restrict__ scores, unsigned char* __restrict__ keep) {
  const int h = blockIdx.x;
  const int tid = threadIdx.x;
  const int MS = 409, ME = 1844, REGN = 1435, KSEL = 204;
  __shared__ float sv[1435];
  __shared__ int cnt, eqn;
  __shared__ int eqlist[256];
  for (int i = tid; i < REGN; i += 256) sv[i] = scores[h * S_LEN + MS + i];
  for (int i = tid; i < S_LEN; i += 256)
    keep[h * S_LEN + i] = (i < MS || i >= ME) ? 1 : 0;
  __syncthreads();
  unsigned lo = 0u, hi = 0x7f800000u;
  while (hi - lo > 1u) {
    unsigned mid = lo + ((hi - lo) >> 1);
    if (tid == 0) cnt = 0;
    __syncthreads();
    int lc = 0;
    for (int i = tid; i < REGN; i += 256) lc += (__float_as_uint(sv[i]) >= mid) ? 1 : 0;
    if (lc) atomicAdd(&cnt, lc);
    __syncthreads();
    int c = cnt;
    __syncthreads();
    if (c >= KSEL) lo = mid;
    else hi = mid;
  }
  if (tid == 0) { cnt = 0; eqn = 0; }
  __syncthreads();
  int lgt = 0;
  for (int i = tid; i < REGN; i += 256) {
    unsigned b = __float_as_uint(sv[i]);
    if (b > lo) { keep[h * S_LEN + MS + i] = 1; lgt++; }
    else if (b == lo) {
      int p = atomicAdd(&eqn, 1);
      if (p < 256) eqlist[p] = i;
    }
  }
  if (lgt) atomicAdd(&cnt, lgt);
  __syncthreads();
  if (tid == 0) {
    int r = KSEL - cnt;
    int ne = eqn > 256 ? 256 : eqn;
    for (int t = 0; t < r; ++t) {
      int best = 0x7fffffff, bj = -1;
      for (int j = 0; j < ne; ++j)
        if (eqlist[j] < best) { best = eqlist[j]; bj = j; }
      if (bj < 0) break;
      keep[h * S_LEN + MS + best] = 1;
      eqlist[bj] = 0x7fffffff;
    }
  }
}

// ---------------- pass 4: pruned+renormalized attention output (split QK, split ctx out) ----------------
__global__ __launch_bounds__(256, 1) void attn_out(
    const __hip_bfloat16* __restrict__ qhi, const __hip_bfloat16* __restrict__ qlo,
    const __hip_bfloat16* __restrict__ khi, const __hip_bfloat16* __restrict__ klo,
    const __hip_bfloat16* __restrict__ vt, const float* __restrict__ mbuf,
    const unsigned char* __restrict__ keep,
    __hip_bfloat16* __restrict__ ctx_h, __hip_bfloat16* __restrict__ ctx_l) {
  __shared__ __hip_bfloat16 Qh[128 * 128];   // 32 KB
  __shared__ __hip_bfloat16 Ql[128 * 128];   // 32 KB
  __shared__ __hip_bfloat16 Kh[64 * 128];    // 16 KB
  __shared__ __hip_bfloat16 Kl[64 * 128];    // 16 KB
  __shared__ __hip_bfloat16 Vtl[128 * 64];   // 16 KB
  __shared__ __hip_bfloat16 Wt[128 * 64];    // 16 KB -> 128 KB total
  const int qt = blockIdx.x, h = blockIdx.y;
  const int hkv = h / NREP;
  const int tid = threadIdx.x;
  const int lane = tid & 63, wid = tid >> 6;
  const int l15 = lane & 15, l4 = lane >> 4;
  stage128(Qh, qhi + (size_t)(qt * 128) * HID + h * HD, HID, tid);
  stage128(Ql, qlo + (size_t)(qt * 128) * HID + h * HD, HID, tid);
  float mrow[2][4];
#pragma unroll
  for (int m = 0; m < 2; ++m)
#pragma unroll
    for (int r = 0; r < 4; ++r) {
      int row = qt * 128 + wid * 32 + m * 16 + l4 * 4 + r;
      mrow[m][r] = mbuf[h * S_LEN + row];
    }
  f32x4 o[2][8] = {};
  float dens[2][4] = {};
  const int nkt = 2 * qt + 2;  // 64-wide K blocks
  for (int kt = 0; kt < nkt; ++kt) {
    __syncthreads();
    stage64_128(Kh, khi + (size_t)(kt * 64) * 512 + hkv * HD, 512, tid);
    stage64_128(Kl, klo + (size_t)(kt * 64) * 512 + hkv * HD, 512, tid);
    stage128_64(Vtl, vt + (size_t)hkv * (HD * S_LEN) + kt * 64, S_LEN, tid);
    __syncthreads();
    // QK^T 3-term over 64 keys
    f32x4 acc[2][4] = {};
#pragma unroll
    for (int kk = 0; kk < 4; ++kk) {
      bf16x8 ah[2], al[2];
#pragma unroll
      for (int m = 0; m < 2; ++m) {
        ah[m] = *(const bf16x8*)&Qh[(wid * 32 + m * 16 + l15) * 128 + kk * 32 + l4 * 8];
        al[m] = *(const bf16x8*)&Ql[(wid * 32 + m * 16 + l15) * 128 + kk * 32 + l4 * 8];
      }
#pragma unroll
      for (int n = 0; n < 4; ++n) {
        bf16x8 bh = *(const bf16x8*)&Kh[(n * 16 + l15) * 128 + kk * 32 + l4 * 8];
        bf16x8 bl = *(const bf16x8*)&Kl[(n * 16 + l15) * 128 + kk * 32 + l4 * 8];
#pragma unroll
        for (int m = 0; m < 2; ++m) {
          acc[m][n] = MFMA_B16(ah[m], bh, acc[m][n]);
          acc[m][n] = MFMA_B16(ah[m], bl, acc[m][n]);
          acc[m][n] = MFMA_B16(al[m], bh, acc[m][n]);
        }
      }
    }
    // weights + Wt (each wave writes/reads only its own 32 rows)
#pragma unroll
    for (int m = 0; m < 2; ++m)
#pragma unroll
      for (int r = 0; r < 4; ++r) {
        int rowg = qt * 128 + wid * 32 + m * 16 + l4 * 4 + r;
        int rowl = wid * 32 + m * 16 + l4 * 4 + r;
#pragma unroll
        for (int n = 0; n < 4; ++n) {
          int coll = n * 16 + l15;
          int colg = kt * 64 + coll;
          float wv = 0.f;
          if (colg <= rowg) {
            float kf = (float)keep[h * S_LEN + colg];
            wv = kf * __expf(acc[m][n][r] * SCALE - mrow[m][r]);
          }
          dens[m][r] += wv;
          Wt[rowl * 64 + coll] = __float2bfloat16(wv);
        }
      }
    // PV: o[row][d] += W[row][k] * Vt[d][k]
#pragma unroll
    for (int kk = 0; kk < 2; ++kk) {
      bf16x8 af[2];
#pragma unroll
      for (int m = 0; m < 2; ++m)
        af[m] = *(const bf16x8*)&Wt[(wid * 32 + m * 16 + l15) * 64 + kk * 32 + l4 * 8];
#pragma unroll
      for (int n = 0; n < 8; ++n) {
        bf16x8 bf = *(const bf16x8*)&Vtl[(n * 16 + l15) * 64 + kk * 32 + l4 * 8];
#pragma unroll
        for (int m = 0; m < 2; ++m)
          o[m][n] = MFMA_B16(af[m], bf, o[m][n]);
      }
    }
  }
  float invd[2][4];
#pragma unroll
  for (int m = 0; m < 2; ++m)
#pragma unroll
    for (int r = 0; r < 4; ++r) {
      float d = dens[m][r];
      d += __shfl_xor(d, 1);
      d += __shfl_xor(d, 2);
      d += __shfl_xor(d, 4);
      d += __shfl_xor(d, 8);
      invd[m][r] = 1.0f / fmaxf(d, 1e-20f);
    }
#pragma unroll
  for (int m = 0; m < 2; ++m)
#pragma unroll
    for (int n = 0; n < 8; ++n)
#pragma unroll
      for (int r = 0; r < 4; ++r) {
        size_t row = qt * 128 + wid * 32 + m * 16 + l4 * 4 + r;
        size_t col = h * HD + n * 16 + l15;
        float val = o[m][n][r] * invd[m][r];
        __hip_bfloat16 hv, lv;
        split2(val, hv, lv);
        ctx_h[row * HID + col] = hv;
        ctx_l[row * HID + col] = lv;
      }
}

// ---------------- host glue ----------------
extern "C" void kernel_launch(void* const* d_in, const int* in_sizes, int n_in,
                              void* d_out, int out_size, void* d_ws, size_t ws_size,
                              hipStream_t stream) {
  const float* hidden = (const float*)d_in[0];
  const float* cosb = (const float*)d_in[2];
  const float* sinb = (const float*)d_in[3];
  const float* q_w = (const float*)d_in[4];
  const float* q_b = (const float*)d_in[5];
  const float* k_w = (const float*)d_in[6];
  const float* k_b = (const float*)d_in[7];
  const float* v_w = (const float*)d_in[8];
  const float* v_b = (const float*)d_in[9];
  const float* o_w = (const float*)d_in[10];

  char* ws = (char*)d_ws;
  // Phase A (QKV GEMM): peak 133.2 MB
  float* qkv_f32 = (float*)(ws + 0);                        // 37,748,736
  __hip_bfloat16* hh = (__hip_bfloat16*)(ws + 37748736);    // 14,680,064
  __hip_bfloat16* hl = (__hip_bfloat16*)(ws + 52428800);    // 14,680,064
  __hip_bfloat16* wqkvh = (__hip_bfloat16*)(ws + 67108864); // 33,030,144
  __hip_bfloat16* wqkvl = (__hip_bfloat16*)(ws + 100139008);// 33,030,144 -> 133,169,152
  float* biasb = (float*)(ws + 133169152);                  //     18,432 -> 133,187,584 peak
  // Phase B overlays (hh/hl dead after QKV gemm; rope writes these):
  __hip_bfloat16* qhi = (__hip_bfloat16*)(ws + 37748736);   // 14,680,064
  __hip_bfloat16* qlo = (__hip_bfloat16*)(ws + 52428800);   // 14,680,064
  // (wqkv dead after QKV gemm):
  __hip_bfloat16* wo_h = (__hip_bfloat16*)(ws + 67108864);  // 25,690,112
  __hip_bfloat16* wo_l = (__hip_bfloat16*)(ws + 92798976);  // 25,690,112 -> 118,489,088
  __hip_bfloat16* khi = (__hip_bfloat16*)(ws + 118489088);  //  2,097,152
  __hip_bfloat16* klo = (__hip_bfloat16*)(ws + 120586240);  //  2,097,152
  __hip_bfloat16* vt = (__hip_bfloat16*)(ws + 122683392);   //  2,097,152
  float* mbuf = (float*)(ws + 124780544);                   //    229,376
  float* lbuf = (float*)(ws + 125009920);                   //    229,376
  float* scores = (float*)(ws + 125239296);                 //    229,376
  unsigned char* keep = (unsigned char*)(ws + 125468672);   //     57,344 -> 125,526,016
  // Phase C overlays (qkv_f32 dead after rope+vtrans):
  __hip_bfloat16* ctx_h = (__hip_bfloat16*)(ws + 0);        // 14,680,064
  __hip_bfloat16* ctx_l = (__hip_bfloat16*)(ws + 14680064); // 14,680,064 -> 29,360,128

  hipMemcpyAsync(biasb, q_b, 3584 * 4, hipMemcpyDeviceToDevice, stream);
  hipMemcpyAsync(biasb + 3584, k_b, 512 * 4, hipMemcpyDeviceToDevice, stream);
  hipMemcpyAsync(biasb + 4096, v_b, 512 * 4, hipMemcpyDeviceToDevice, stream);

  // pre-split GEMM operands
  split_f32_bf16<<<7168, 256, 0, stream>>>(hidden, hh, hl, 1835008);
  split_f32_bf16<<<12544, 256, 0, stream>>>(q_w, wqkvh, wqkvl, 3211264);
  split_f32_bf16<<<1792, 256, 0, stream>>>(k_w, wqkvh + (size_t)3584 * 3584,
                                           wqkvl + (size_t)3584 * 3584, 458752);
  split_f32_bf16<<<1792, 256, 0, stream>>>(v_w, wqkvh + (size_t)4096 * 3584,
                                           wqkvl + (size_t)4096 * 3584, 458752);

  // QKV projection, fp32-grade 3-term GEMM (+bias)
  gemm3t<true><<<dim3(36, 16), 256, 0, stream>>>(hh, hl, HID, wqkvh, wqkvl, HID,
                                                 biasb, qkv_f32, QKV_N, HID);

  // o_w split into now-dead wqkv space (stream-ordered)
  split_f32_bf16<<<12544, 256, 0, stream>>>(o_w, wo_h, wo_l, 3211264);

  rope_split<<<16384, 256, 0, stream>>>(qkv_f32, cosb, sinb, qhi, qlo, khi, klo);
  vtrans<<<dim3(32, 2, 4), 256, 0, stream>>>(qkv_f32, vt);
  hipMemsetAsync(scores, 0, NHEADS * S_LEN * 4, stream);

  attn_stats_lite<<<dim3(16, 28), 256, 0, stream>>>(qhi, khi, mbuf, lbuf);
  attn_scores<<<dim3(16, 28), 256, 0, stream>>>(qhi, qlo, khi, klo, mbuf, lbuf, scores);
  h2o_topk<<<28, 256, 0, stream>>>(scores, keep);
  attn_out<<<dim3(16, 28), 256, 0, stream>>>(qhi, qlo, khi, klo, vt, mbuf, keep, ctx_h, ctx_l);

  // output projection, fp32-grade 3-term GEMM
  gemm3t<false><<<dim3(28, 16), 256, 0, stream>>>(ctx_h, ctx_l, HID, wo_h, wo_l, HID,
                                                  nullptr, (float*)d_out, HID, HID);
}

// Round 6
// 882.428 us; speedup vs baseline: 1.9491x; 1.4656x over previous
//
#include <hip/hip_runtime.h>
#include <hip/hip_bf16.h>
#include <stdint.h>

#define S_LEN 2048
#define HID 3584
#define NHEADS 28
#define KVHEADS 4
#define HD 128
#define QKV_N 4608
#define NREP 7
#define SCALE 0.08838834764831845f

typedef __attribute__((ext_vector_type(8))) short bf16x8;
typedef __attribute__((ext_vector_type(4))) float f32x4;

#define MFMA_B16(a, b, c) __builtin_amdgcn_mfma_f32_16x16x32_bf16((a), (b), (c), 0, 0, 0)

__device__ __forceinline__ void gl_lds16(const void* g, void* l) {
  __builtin_amdgcn_global_load_lds(
      (__attribute__((address_space(1))) void*)(void*)(g),
      (__attribute__((address_space(3))) void*)(l), 16, 0, 0);
}

__device__ __forceinline__ void split2(float x, __hip_bfloat16& h, __hip_bfloat16& l) {
  h = __float2bfloat16(x);
  l = __float2bfloat16(x - __bfloat162float(h));
}

// ---------------- fp32 -> (hi, lo) bf16 split ----------------
__global__ void split_f32_bf16(const float* __restrict__ src, __hip_bfloat16* __restrict__ hi,
                               __hip_bfloat16* __restrict__ lo, int n4) {
  int i = blockIdx.x * 256 + threadIdx.x;
  if (i >= n4) return;
  float4 v = ((const float4*)src)[i];
  __hip_bfloat16 th[4], tl[4];
  float x[4] = {v.x, v.y, v.z, v.w};
#pragma unroll
  for (int u = 0; u < 4; ++u) split2(x[u], th[u], tl[u]);
  ((uint2*)hi)[i] = *(const uint2*)th;
  ((uint2*)lo)[i] = *(const uint2*)tl;
}

// ---------------- pre-split 3-term GEMM: C = (Ah+Al)*(Bh+Bl)^T (+bias) ----------------
template <bool HAS_BIAS>
__global__ __launch_bounds__(256, 2) void gemm3t(
    const __hip_bfloat16* __restrict__ Ahg, const __hip_bfloat16* __restrict__ Alg, int lda,
    const __hip_bfloat16* __restrict__ Bhg, const __hip_bfloat16* __restrict__ Blg, int ldb,
    const float* __restrict__ bias, float* __restrict__ C, int ldc, int K) {
  __shared__ __hip_bfloat16 lAh[128 * 32], lAl[128 * 32], lBh[128 * 32], lBl[128 * 32];
  const int tid = threadIdx.x;
  const int lane = tid & 63;
  const int wid = tid >> 6;
  const int wr = wid >> 1, wc = wid & 1;
  const int l15 = lane & 15, l4 = lane >> 4;
  const int bm = blockIdx.y * 128, bn = blockIdx.x * 128;
  f32x4 acc[4][4] = {};
  for (int k0 = 0; k0 < K; k0 += 32) {
    __syncthreads();
#pragma unroll
    for (int it = 0; it < 2; ++it) {
      int c = it * 256 + tid;
      int row = c >> 2, col = (c & 3) << 3;
      int lo = (it * 256 + (tid & 192)) * 8;
      gl_lds16(Ahg + (size_t)(bm + row) * lda + (k0 + col), &lAh[lo]);
      gl_lds16(Alg + (size_t)(bm + row) * lda + (k0 + col), &lAl[lo]);
      gl_lds16(Bhg + (size_t)(bn + row) * ldb + (k0 + col), &lBh[lo]);
      gl_lds16(Blg + (size_t)(bn + row) * ldb + (k0 + col), &lBl[lo]);
    }
    __syncthreads();
    bf16x8 ah[4], al[4], bh[4], bl[4];
#pragma unroll
    for (int m = 0; m < 4; ++m) {
      ah[m] = *(const bf16x8*)&lAh[(wr * 64 + m * 16 + l15) * 32 + l4 * 8];
      al[m] = *(const bf16x8*)&lAl[(wr * 64 + m * 16 + l15) * 32 + l4 * 8];
    }
#pragma unroll
    for (int n = 0; n < 4; ++n) {
      bh[n] = *(const bf16x8*)&lBh[(wc * 64 + n * 16 + l15) * 32 + l4 * 8];
      bl[n] = *(const bf16x8*)&lBl[(wc * 64 + n * 16 + l15) * 32 + l4 * 8];
    }
#pragma unroll
    for (int m = 0; m < 4; ++m)
#pragma unroll
      for (int n = 0; n < 4; ++n) {
        acc[m][n] = MFMA_B16(ah[m], bh[n], acc[m][n]);
        acc[m][n] = MFMA_B16(ah[m], bl[n], acc[m][n]);
        acc[m][n] = MFMA_B16(al[m], bh[n], acc[m][n]);
      }
  }
#pragma unroll
  for (int m = 0; m < 4; ++m)
#pragma unroll
    for (int n = 0; n < 4; ++n)
#pragma unroll
      for (int r = 0; r < 4; ++r) {
        size_t row = bm + wr * 64 + m * 16 + l4 * 4 + r;
        size_t col = bn + wc * 64 + n * 16 + l15;
        float v = acc[m][n][r];
        if (HAS_BIAS) v += bias[col];
        C[row * ldc + col] = v;
      }
}

// ---------------- rope on fp32 qkv, emit split bf16 Q/K ----------------
__global__ void rope_split(const float* __restrict__ qf, const float* __restrict__ cb,
                           const float* __restrict__ sb,
                           __hip_bfloat16* __restrict__ qhi, __hip_bfloat16* __restrict__ qlo,
                           __hip_bfloat16* __restrict__ khi, __hip_bfloat16* __restrict__ klo) {
  int idx = blockIdx.x * 256 + threadIdx.x;  // 2048 * 32 * 64
  int d1 = idx & 63;
  int hh = (idx >> 6) & 31;
  int s = idx >> 11;
  if (s >= S_LEN) return;
  const float* row = qf + (size_t)s * QKV_N + (hh < NHEADS ? hh * HD : HID + (hh - NHEADS) * HD);
  int d2 = d1 + 64;
  int ax1 = (d1 < 32) ? 0 : 1;  // sections: [0,32)->ax0, [32,80)->ax1, [80,128)->ax2
  int ax2 = (d2 < 80) ? 1 : 2;
  float c1 = cb[(size_t)ax1 * S_LEN * HD + (size_t)s * HD + d1];
  float s1 = sb[(size_t)ax1 * S_LEN * HD + (size_t)s * HD + d1];
  float c2 = cb[(size_t)ax2 * S_LEN * HD + (size_t)s * HD + d2];
  float s2 = sb[(size_t)ax2 * S_LEN * HD + (size_t)s * HD + d2];
  float x1 = row[d1], x2 = row[d2];
  float y1 = x1 * c1 - x2 * s1;
  float y2 = x2 * c2 + x1 * s2;
  __hip_bfloat16 *dh, *dl;
  size_t base;
  if (hh < NHEADS) { dh = qhi; dl = qlo; base = (size_t)s * HID + hh * HD; }
  else { dh = khi; dl = klo; base = (size_t)s * 512 + (hh - NHEADS) * HD; }
  __hip_bfloat16 h1, l1, h2, l2;
  split2(y1, h1, l1);
  split2(y2, h2, l2);
  dh[base + d1] = h1; dl[base + d1] = l1;
  dh[base + d2] = h2; dl[base + d2] = l2;
}

// ---------------- V transpose from fp32 qkv: vt[j][d][k] ----------------
__global__ void vtrans(const float* __restrict__ qf, __hip_bfloat16* __restrict__ vt) {
  __shared__ __hip_bfloat16 t[64][65];
  const int j = blockIdx.z;
  const int d0 = blockIdx.y * 64;
  const int k0 = blockIdx.x * 64;
  const int tid = threadIdx.x;
#pragma unroll
  for (int half = 0; half < 2; ++half) {
    int r = half * 32 + (tid >> 3);
    int c = (tid & 7) * 8;
    const float* p = qf + (size_t)(k0 + r) * QKV_N + (HID + 512) + j * HD + d0 + c;
    float4 a = ((const float4*)p)[0];
    float4 b = ((const float4*)p)[1];
    t[c + 0][r] = __float2bfloat16(a.x); t[c + 1][r] = __float2bfloat16(a.y);
    t[c + 2][r] = __float2bfloat16(a.z); t[c + 3][r] = __float2bfloat16(a.w);
    t[c + 4][r] = __float2bfloat16(b.x); t[c + 5][r] = __float2bfloat16(b.y);
    t[c + 6][r] = __float2bfloat16(b.z); t[c + 7][r] = __float2bfloat16(b.w);
  }
  __syncthreads();
#pragma unroll
  for (int half = 0; half < 2; ++half) {
    int r = half * 32 + (tid >> 3);
    int c = (tid & 7) * 8;
    __hip_bfloat16 tmp[8];
#pragma unroll
    for (int u = 0; u < 8; ++u) tmp[u] = t[r][c + u];
    *(bf16x8*)&vt[(size_t)j * (HD * S_LEN) + (size_t)(d0 + r) * S_LEN + k0 + c] = *(const bf16x8*)tmp;
  }
}

// ------------- swizzled staging: LDS linear dest, pre-swizzled global src -------------
// 64 rows x 128 cols (16 slots/row of 8 bf16): slot ^= row&7
__device__ __forceinline__ void stageK_sw(__hip_bfloat16* dst, const __hip_bfloat16* gsrc,
                                          int ldg, int tid) {
#pragma unroll
  for (int it = 0; it < 4; ++it) {
    int c = it * 256 + tid;
    int rw = c >> 4, sl = c & 15;
    int gcol = (sl ^ (rw & 7)) << 3;
    gl_lds16(gsrc + (size_t)rw * ldg + gcol, dst + (size_t)(it * 256 + (tid & 192)) * 8);
  }
}
// 128 rows x 64 cols (8 slots/row): slot ^= row&7
__device__ __forceinline__ void stageV_sw(__hip_bfloat16* dst, const __hip_bfloat16* gsrc,
                                          int ldg, int tid) {
#pragma unroll
  for (int it = 0; it < 4; ++it) {
    int c = it * 256 + tid;
    int rw = c >> 3, sl = c & 7;
    int gcol = (sl ^ (rw & 7)) << 3;
    gl_lds16(gsrc + (size_t)rw * ldg + gcol, dst + (size_t)(it * 256 + (tid & 192)) * 8);
  }
}

// ---------------- pass 1: row max + sumexp, 1-term (hi-only) logits ----------------
__global__ __launch_bounds__(256, 2) void attn_stats_lite(
    const __hip_bfloat16* __restrict__ qhi, const __hip_bfloat16* __restrict__ khi,
    float* __restrict__ mbuf, float* __restrict__ lbuf) {
  __shared__ __hip_bfloat16 Kh[64 * 128];  // 16 KB
  const int qb = 31 - blockIdx.x, h = blockIdx.y;
  const int hkv = h / NREP;
  const int tid = threadIdx.x;
  const int lane = tid & 63, w = tid >> 6;
  const int l15 = lane & 15, l4 = lane >> 4;
  const int sw = (l15 & 7);
  bf16x8 qh[4];
  {
    const __hip_bfloat16* qp = qhi + (size_t)(qb * 64 + w * 16 + l15) * HID + h * HD + l4 * 8;
#pragma unroll
    for (int kk = 0; kk < 4; ++kk) qh[kk] = *(const bf16x8*)(qp + kk * 32);
  }
  float m_run[4], l_run[4];
#pragma unroll
  for (int r = 0; r < 4; ++r) { m_run[r] = -1e30f; l_run[r] = 0.f; }
  const int nkt = qb + 1;
  for (int kt = 0; kt < nkt; ++kt) {
    __syncthreads();
    stageK_sw(Kh, khi + (size_t)(kt * 64) * 512 + hkv * HD, 512, tid);
    __syncthreads();
    f32x4 acc[4] = {};
#pragma unroll
    for (int kk = 0; kk < 4; ++kk) {
#pragma unroll
      for (int n = 0; n < 4; ++n) {
        bf16x8 bh = *(const bf16x8*)&Kh[(n * 16 + l15) * 128 + (((kk * 4 + l4) ^ sw) << 3)];
        acc[n] = MFMA_B16(qh[kk], bh, acc[n]);
      }
    }
    const bool diag = (kt == qb);
#pragma unroll
    for (int r = 0; r < 4; ++r) {
      int rowg = qb * 64 + w * 16 + l4 * 4 + r;
      float v[4], tmax = -1e30f;
#pragma unroll
      for (int n = 0; n < 4; ++n) {
        float x = acc[n][r] * SCALE;
        if (diag && (kt * 64 + n * 16 + l15) > rowg) x = -1e30f;
        v[n] = x;
        tmax = fmaxf(tmax, x);
      }
      tmax = fmaxf(tmax, __shfl_xor(tmax, 1));
      tmax = fmaxf(tmax, __shfl_xor(tmax, 2));
      tmax = fmaxf(tmax, __shfl_xor(tmax, 4));
      tmax = fmaxf(tmax, __shfl_xor(tmax, 8));
      float mold = m_run[r];
      float mnew = fmaxf(mold, tmax);
      float sum = 0.f;
#pragma unroll
      for (int n = 0; n < 4; ++n) sum += __expf(v[n] - mnew);
      sum += __shfl_xor(sum, 1);
      sum += __shfl_xor(sum, 2);
      sum += __shfl_xor(sum, 4);
      sum += __shfl_xor(sum, 8);
      l_run[r] = l_run[r] * __expf(mold - mnew) + sum;
      m_run[r] = mnew;
    }
  }
  if (l15 == 0) {
#pragma unroll
    for (int r = 0; r < 4; ++r) {
      int row = qb * 64 + w * 16 + l4 * 4 + r;
      mbuf[h * S_LEN + row] = m_run[r];
      lbuf[h * S_LEN + row] = l_run[r];
    }
  }
}

// ---------------- pass 2: per-key accumulated softmax mass (split logits) ----------------
__global__ __launch_bounds__(256, 2) void attn_scores(
    const __hip_bfloat16* __restrict__ qhi, const __hip_bfloat16* __restrict__ qlo,
    const __hip_bfloat16* __restrict__ khi, const __hip_bfloat16* __restrict__ klo,
    const float* __restrict__ mbuf, const float* __restrict__ lbuf,
    float* __restrict__ scores) {
  __shared__ __hip_bfloat16 Kh[64 * 128], Kl[64 * 128];  // 32 KB
  const int qb = 31 - blockIdx.x, h = blockIdx.y;
  const int hkv = h / NREP;
  const int tid = threadIdx.x;
  const int lane = tid & 63, w = tid >> 6;
  const int l15 = lane & 15, l4 = lane >> 4;
  const int sw = (l15 & 7);
  bf16x8 qh[4], ql[4];
  {
    const size_t qoff = (size_t)(qb * 64 + w * 16 + l15) * HID + h * HD + l4 * 8;
#pragma unroll
    for (int kk = 0; kk < 4; ++kk) {
      qh[kk] = *(const bf16x8*)(qhi + qoff + kk * 32);
      ql[kk] = *(const bf16x8*)(qlo + qoff + kk * 32);
    }
  }
  float mrow[4], invl[4];
#pragma unroll
  for (int r = 0; r < 4; ++r) {
    int row = qb * 64 + w * 16 + l4 * 4 + r;
    mrow[r] = mbuf[h * S_LEN + row];
    invl[r] = 1.0f / lbuf[h * S_LEN + row];
  }
  const int nkt = qb + 1;
  for (int kt = 0; kt < nkt; ++kt) {
    __syncthreads();
    stageK_sw(Kh, khi + (size_t)(kt * 64) * 512 + hkv * HD, 512, tid);
    stageK_sw(Kl, klo + (size_t)(kt * 64) * 512 + hkv * HD, 512, tid);
    __syncthreads();
    f32x4 acc[4] = {};
#pragma unroll
    for (int kk = 0; kk < 4; ++kk) {
#pragma unroll
      for (int n = 0; n < 4; ++n) {
        int off = (n * 16 + l15) * 128 + (((kk * 4 + l4) ^ sw) << 3);
        bf16x8 bh = *(const bf16x8*)&Kh[off];
        bf16x8 bl = *(const bf16x8*)&Kl[off];
        acc[n] = MFMA_B16(qh[kk], bh, acc[n]);
        acc[n] = MFMA_B16(qh[kk], bl, acc[n]);
        acc[n] = MFMA_B16(ql[kk], bh, acc[n]);
      }
    }
    const bool diag = (kt == qb);
    float colsum[4] = {0.f, 0.f, 0.f, 0.f};
#pragma unroll
    for (int r = 0; r < 4; ++r) {
      int rowg = qb * 64 + w * 16 + l4 * 4 + r;
#pragma unroll
      for (int n = 0; n < 4; ++n) {
        float x = acc[n][r] * SCALE;
        if (!(diag && (kt * 64 + n * 16 + l15) > rowg))
          colsum[n] += __expf(x - mrow[r]) * invl[r];
      }
    }
#pragma unroll
    for (int n = 0; n < 4; ++n) {
      colsum[n] += __shfl_xor(colsum[n], 16);
      colsum[n] += __shfl_xor(colsum[n], 32);
    }
    if (lane < 16) {
#pragma unroll
      for (int n = 0; n < 4; ++n)
        atomicAdd(&scores[h * S_LEN + kt * 64 + n * 16 + lane], colsum[n]);
    }
  }
}

// ---------------- pass 3: exact top-k (boundary search) -> keep mask ----------------
__global__ void h2o_topk(const float* __restrict__ scores, unsigned char* __restrict__ keep) {
  const int h = blockIdx.x;
  const int tid = threadIdx.x;
  const int MS = 409, ME = 1844, REGN = 1435, KSEL = 204;
  __shared__ float sv[1435];
  __shared__ int cnt, eqn;
  __shared__ int eqlist[256];
  for (int i = tid; i < REGN; i += 256) sv[i] = scores[h * S_LEN + MS + i];
  for (int i = tid; i < S_LEN; i += 256)
    keep[h * S_LEN + i] = (i < MS || i >= ME) ? 1 : 0;
  __syncthreads();
  unsigned lo = 0u, hi = 0x7f800000u;
  while (hi - lo > 1u) {
    unsigned mid = lo + ((hi - lo) >> 1);
    if (tid == 0) cnt = 0;
    __syncthreads();
    int lc = 0;
    for (int i = tid; i < REGN; i += 256) lc += (__float_as_uint(sv[i]) >= mid) ? 1 : 0;
    if (lc) atomicAdd(&cnt, lc);
    __syncthreads();
    int c = cnt;
    __syncthreads();
    if (c >= KSEL) lo = mid;
    else hi = mid;
  }
  if (tid == 0) { cnt = 0; eqn = 0; }
  __syncthreads();
  int lgt = 0;
  for (int i = tid; i < REGN; i += 256) {
    unsigned b = __float_as_uint(sv[i]);
    if (b > lo) { keep[h * S_LEN + MS + i] = 1; lgt++; }
    else if (b == lo) {
      int p = atomicAdd(&eqn, 1);
      if (p < 256) eqlist[p] = i;
    }
  }
  if (lgt) atomicAdd(&cnt, lgt);
  __syncthreads();
  if (tid == 0) {
    int r = KSEL - cnt;
    int ne = eqn > 256 ? 256 : eqn;
    for (int t = 0; t < r; ++t) {
      int best = 0x7fffffff, bj = -1;
      for (int j = 0; j < ne; ++j)
        if (eqlist[j] < best) { best = eqlist[j]; bj = j; }
      if (bj < 0) break;
      keep[h * S_LEN + MS + best] = 1;
      eqlist[bj] = 0x7fffffff;
    }
  }
}

// ---------------- pass 4: pruned+renormalized attention output ----------------
__global__ __launch_bounds__(256, 2) void attn_out(
    const __hip_bfloat16* __restrict__ qhi, const __hip_bfloat16* __restrict__ qlo,
    const __hip_bfloat16* __restrict__ khi, const __hip_bfloat16* __restrict__ klo,
    const __hip_bfloat16* __restrict__ vt, const float* __restrict__ mbuf,
    const unsigned char* __restrict__ keep,
    __hip_bfloat16* __restrict__ ctx_h, __hip_bfloat16* __restrict__ ctx_l) {
  __shared__ __hip_bfloat16 Kh[64 * 128];   // 16 KB
  __shared__ __hip_bfloat16 Kl[64 * 128];   // 16 KB
  __shared__ __hip_bfloat16 Vtl[128 * 64];  // 16 KB
  __shared__ __hip_bfloat16 Wt[4 * 16 * 64];// 8 KB -> 56 KB total (2 blocks/CU)
  const int qb = 31 - blockIdx.x, h = blockIdx.y;
  const int hkv = h / NREP;
  const int tid = threadIdx.x;
  const int lane = tid & 63, w = tid >> 6;
  const int l15 = lane & 15, l4 = lane >> 4;
  const int sw = (l15 & 7);
  bf16x8 qh[4], ql[4];
  {
    const size_t qoff = (size_t)(qb * 64 + w * 16 + l15) * HID + h * HD + l4 * 8;
#pragma unroll
    for (int kk = 0; kk < 4; ++kk) {
      qh[kk] = *(const bf16x8*)(qhi + qoff + kk * 32);
      ql[kk] = *(const bf16x8*)(qlo + qoff + kk * 32);
    }
  }
  float mrow[4];
#pragma unroll
  for (int r = 0; r < 4; ++r)
    mrow[r] = mbuf[h * S_LEN + qb * 64 + w * 16 + l4 * 4 + r];
  f32x4 o[8] = {};
  float dens[4] = {0.f, 0.f, 0.f, 0.f};
  const int nkt = qb + 1;
  for (int kt = 0; kt < nkt; ++kt) {
    __syncthreads();
    stageK_sw(Kh, khi + (size_t)(kt * 64) * 512 + hkv * HD, 512, tid);
    stageK_sw(Kl, klo + (size_t)(kt * 64) * 512 + hkv * HD, 512, tid);
    stageV_sw(Vtl, vt + (size_t)hkv * (HD * S_LEN) + kt * 64, S_LEN, tid);
    __syncthreads();
    // QK^T 3-term over 64 keys
    f32x4 acc[4] = {};
#pragma unroll
    for (int kk = 0; kk < 4; ++kk) {
#pragma unroll
      for (int n = 0; n < 4; ++n) {
        int off = (n * 16 + l15) * 128 + (((kk * 4 + l4) ^ sw) << 3);
        bf16x8 bh = *(const bf16x8*)&Kh[off];
        bf16x8 bl = *(const bf16x8*)&Kl[off];
        acc[n] = MFMA_B16(qh[kk], bh, acc[n]);
        acc[n] = MFMA_B16(qh[kk], bl, acc[n]);
        acc[n] = MFMA_B16(ql[kk], bh, acc[n]);
      }
    }
    const bool diag = (kt == qb);
    float kf[4];
#pragma unroll
    for (int n = 0; n < 4; ++n)
      kf[n] = (float)keep[h * S_LEN + kt * 64 + n * 16 + l15];
#pragma unroll
    for (int r = 0; r < 4; ++r) {
      int rowg = qb * 64 + w * 16 + l4 * 4 + r;
      int row16 = l4 * 4 + r;
#pragma unroll
      for (int n = 0; n < 4; ++n) {
        int coll = n * 16 + l15;
        float wv = 0.f;
        if (!diag || (kt * 64 + coll) <= rowg)
          wv = kf[n] * __expf(acc[n][r] * SCALE - mrow[r]);
        dens[r] += wv;
        Wt[w * 1024 + row16 * 64 + (coll ^ ((row16 & 7) << 3))] = __float2bfloat16(wv);
      }
    }
    // PV: o[n] += W(16x64) * Vt(row=d)
#pragma unroll
    for (int kk = 0; kk < 2; ++kk) {
      bf16x8 af = *(const bf16x8*)&Wt[w * 1024 + l15 * 64 + ((kk * 32 + l4 * 8) ^ (sw << 3))];
#pragma unroll
      for (int n = 0; n < 8; ++n) {
        bf16x8 bf = *(const bf16x8*)&Vtl[(n * 16 + l15) * 64 + (((kk * 4 + l4) ^ sw) << 3)];
        o[n] = MFMA_B16(af, bf, o[n]);
      }
    }
  }
  float invd[4];
#pragma unroll
  for (int r = 0; r < 4; ++r) {
    float d = dens[r];
    d += __shfl_xor(d, 1);
    d += __shfl_xor(d, 2);
    d += __shfl_xor(d, 4);
    d += __shfl_xor(d, 8);
    invd[r] = 1.0f / fmaxf(d, 1e-20f);
  }
#pragma unroll
  for (int n = 0; n < 8; ++n)
#pragma unroll
    for (int r = 0; r < 4; ++r) {
      size_t row = qb * 64 + w * 16 + l4 * 4 + r;
      size_t col = h * HD + n * 16 + l15;
      float val = o[n][r] * invd[r];
      __hip_bfloat16 hv, lv;
      split2(val, hv, lv);
      ctx_h[row * HID + col] = hv;
      ctx_l[row * HID + col] = lv;
    }
}

// ---------------- host glue ----------------
extern "C" void kernel_launch(void* const* d_in, const int* in_sizes, int n_in,
                              void* d_out, int out_size, void* d_ws, size_t ws_size,
                              hipStream_t stream) {
  const float* hidden = (const float*)d_in[0];
  const float* cosb = (const float*)d_in[2];
  const float* sinb = (const float*)d_in[3];
  const float* q_w = (const float*)d_in[4];
  const float* q_b = (const float*)d_in[5];
  const float* k_w = (const float*)d_in[6];
  const float* k_b = (const float*)d_in[7];
  const float* v_w = (const float*)d_in[8];
  const float* v_b = (const float*)d_in[9];
  const float* o_w = (const float*)d_in[10];

  char* ws = (char*)d_ws;
  // Phase A (QKV GEMM): peak 133.2 MB
  float* qkv_f32 = (float*)(ws + 0);                        // 37,748,736
  __hip_bfloat16* hh = (__hip_bfloat16*)(ws + 37748736);    // 14,680,064
  __hip_bfloat16* hl = (__hip_bfloat16*)(ws + 52428800);    // 14,680,064
  __hip_bfloat16* wqkvh = (__hip_bfloat16*)(ws + 67108864); // 33,030,144
  __hip_bfloat16* wqkvl = (__hip_bfloat16*)(ws + 100139008);// 33,030,144 -> 133,169,152
  float* biasb = (float*)(ws + 133169152);                  //     18,432 -> 133,187,584 peak
  // Phase B overlays (hh/hl dead after QKV gemm; rope writes these):
  __hip_bfloat16* qhi = (__hip_bfloat16*)(ws + 37748736);   // 14,680,064
  __hip_bfloat16* qlo = (__hip_bfloat16*)(ws + 52428800);   // 14,680,064
  // (wqkv dead after QKV gemm):
  __hip_bfloat16* wo_h = (__hip_bfloat16*)(ws + 67108864);  // 25,690,112
  __hip_bfloat16* wo_l = (__hip_bfloat16*)(ws + 92798976);  // 25,690,112 -> 118,489,088
  __hip_bfloat16* khi = (__hip_bfloat16*)(ws + 118489088);  //  2,097,152
  __hip_bfloat16* klo = (__hip_bfloat16*)(ws + 120586240);  //  2,097,152
  __hip_bfloat16* vt = (__hip_bfloat16*)(ws + 122683392);   //  2,097,152
  float* mbuf = (float*)(ws + 124780544);                   //    229,376
  float* lbuf = (float*)(ws + 125009920);                   //    229,376
  float* scores = (float*)(ws + 125239296);                 //    229,376
  unsigned char* keep = (unsigned char*)(ws + 125468672);   //     57,344 -> 125,526,016
  // Phase C overlays (qkv_f32 dead after rope+vtrans):
  __hip_bfloat16* ctx_h = (__hip_bfloat16*)(ws + 0);        // 14,680,064
  __hip_bfloat16* ctx_l = (__hip_bfloat16*)(ws + 14680064); // 14,680,064 -> 29,360,128

  hipMemcpyAsync(biasb, q_b, 3584 * 4, hipMemcpyDeviceToDevice, stream);
  hipMemcpyAsync(biasb + 3584, k_b, 512 * 4, hipMemcpyDeviceToDevice, stream);
  hipMemcpyAsync(biasb + 4096, v_b, 512 * 4, hipMemcpyDeviceToDevice, stream);

  // pre-split GEMM operands
  split_f32_bf16<<<7168, 256, 0, stream>>>(hidden, hh, hl, 1835008);
  split_f32_bf16<<<12544, 256, 0, stream>>>(q_w, wqkvh, wqkvl, 3211264);
  split_f32_bf16<<<1792, 256, 0, stream>>>(k_w, wqkvh + (size_t)3584 * 3584,
                                           wqkvl + (size_t)3584 * 3584, 458752);
  split_f32_bf16<<<1792, 256, 0, stream>>>(v_w, wqkvh + (size_t)4096 * 3584,
                                           wqkvl + (size_t)4096 * 3584, 458752);

  // QKV projection, fp32-grade 3-term GEMM (+bias)
  gemm3t<true><<<dim3(36, 16), 256, 0, stream>>>(hh, hl, HID, wqkvh, wqkvl, HID,
                                                 biasb, qkv_f32, QKV_N, HID);

  // o_w split into now-dead wqkv space (stream-ordered)
  split_f32_bf16<<<12544, 256, 0, stream>>>(o_w, wo_h, wo_l, 3211264);

  rope_split<<<16384, 256, 0, stream>>>(qkv_f32, cosb, sinb, qhi, qlo, khi, klo);
  vtrans<<<dim3(32, 2, 4), 256, 0, stream>>>(qkv_f32, vt);
  hipMemsetAsync(scores, 0, NHEADS * S_LEN * 4, stream);

  attn_stats_lite<<<dim3(32, 28), 256, 0, stream>>>(qhi, khi, mbuf, lbuf);
  attn_scores<<<dim3(32, 28), 256, 0, stream>>>(qhi, qlo, khi, klo, mbuf, lbuf, scores);
  h2o_topk<<<28, 256, 0, stream>>>(scores, keep);
  attn_out<<<dim3(32, 28), 256, 0, stream>>>(qhi, qlo, khi, klo, vt, mbuf, keep, ctx_h, ctx_l);

  // output projection, fp32-grade 3-term GEMM
  gemm3t<false><<<dim3(28, 16), 256, 0, stream>>>(ctx_h, ctx_l, HID, wo_h, wo_l, HID,
                                                  nullptr, (float*)d_out, HID, HID);
}

// Round 7
// 662.735 us; speedup vs baseline: 2.5952x; 1.3315x over previous
//
#include <hip/hip_runtime.h>
#include <hip/hip_bf16.h>
#include <stdint.h>

#define S_LEN 2048
#define HID 3584
#define NHEADS 28
#define KVHEADS 4
#define HD 128
#define QKV_N 4608
#define NREP 7
#define SCALE 0.08838834764831845f

typedef __attribute__((ext_vector_type(8))) short bf16x8;
typedef __attribute__((ext_vector_type(8))) _Float16 f16x8;
typedef __attribute__((ext_vector_type(4))) float f32x4;

#define MFMA_B16(a, b, c) __builtin_amdgcn_mfma_f32_16x16x32_bf16((a), (b), (c), 0, 0, 0)
#define MFMA_F16(a, b, c) __builtin_amdgcn_mfma_f32_16x16x32_f16((a), (b), (c), 0, 0, 0)

__device__ __forceinline__ void gl_lds16(const void* g, void* l) {
  __builtin_amdgcn_global_load_lds(
      (__attribute__((address_space(1))) void*)(void*)(g),
      (__attribute__((address_space(3))) void*)(l), 16, 0, 0);
}

__device__ __forceinline__ void split2(float x, __hip_bfloat16& h, __hip_bfloat16& l) {
  h = __float2bfloat16(x);
  l = __float2bfloat16(x - __bfloat162float(h));
}

// ---------------- fp32 -> fp16 conversion ----------------
__global__ void cvt_f32_f16(const float* __restrict__ src, _Float16* __restrict__ dst, int n4) {
  int i = blockIdx.x * 256 + threadIdx.x;
  if (i >= n4) return;
  float4 v = ((const float4*)src)[i];
  _Float16 t[4] = {(_Float16)v.x, (_Float16)v.y, (_Float16)v.z, (_Float16)v.w};
  ((uint2*)dst)[i] = *(const uint2*)t;
}

// ---------------- fp16 GEMM: C = A * B^T (+bias), m97 structure ----------------
template <bool HAS_BIAS>
__global__ __launch_bounds__(256, 2) void gemm_f16(
    const _Float16* __restrict__ A, int lda,
    const _Float16* __restrict__ B, int ldb,
    const float* __restrict__ bias, float* __restrict__ C, int ldc, int K) {
  __shared__ _Float16 lA[128 * 32], lB[128 * 32];
  const int tid = threadIdx.x;
  const int lane = tid & 63;
  const int wid = tid >> 6;
  const int wr = wid >> 1, wc = wid & 1;
  const int l15 = lane & 15, l4 = lane >> 4;
  const int bm = blockIdx.y * 128, bn = blockIdx.x * 128;
  f32x4 acc[4][4] = {};
  for (int k0 = 0; k0 < K; k0 += 32) {
    __syncthreads();
#pragma unroll
    for (int it = 0; it < 2; ++it) {
      int c = it * 256 + tid;
      int row = c >> 2, col = (c & 3) << 3;
      int lo = (it * 256 + (tid & 192)) * 8;
      gl_lds16(A + (size_t)(bm + row) * lda + (k0 + col), &lA[lo]);
      gl_lds16(B + (size_t)(bn + row) * ldb + (k0 + col), &lB[lo]);
    }
    __syncthreads();
    f16x8 af[4], bf[4];
#pragma unroll
    for (int m = 0; m < 4; ++m)
      af[m] = *(const f16x8*)&lA[(wr * 64 + m * 16 + l15) * 32 + l4 * 8];
#pragma unroll
    for (int n = 0; n < 4; ++n)
      bf[n] = *(const f16x8*)&lB[(wc * 64 + n * 16 + l15) * 32 + l4 * 8];
#pragma unroll
    for (int m = 0; m < 4; ++m)
#pragma unroll
      for (int n = 0; n < 4; ++n)
        acc[m][n] = MFMA_F16(af[m], bf[n], acc[m][n]);
  }
#pragma unroll
  for (int m = 0; m < 4; ++m)
#pragma unroll
    for (int n = 0; n < 4; ++n)
#pragma unroll
      for (int r = 0; r < 4; ++r) {
        size_t row = bm + wr * 64 + m * 16 + l4 * 4 + r;
        size_t col = bn + wc * 64 + n * 16 + l15;
        float v = acc[m][n][r];
        if (HAS_BIAS) v += bias[col];
        C[row * ldc + col] = v;
      }
}

// ---------------- rope on fp32 qkv, emit split bf16 Q/K ----------------
__global__ void rope_split(const float* __restrict__ qf, const float* __restrict__ cb,
                           const float* __restrict__ sb,
                           __hip_bfloat16* __restrict__ qhi, __hip_bfloat16* __restrict__ qlo,
                           __hip_bfloat16* __restrict__ khi, __hip_bfloat16* __restrict__ klo) {
  int idx = blockIdx.x * 256 + threadIdx.x;  // 2048 * 32 * 64
  int d1 = idx & 63;
  int hh = (idx >> 6) & 31;
  int s = idx >> 11;
  if (s >= S_LEN) return;
  const float* row = qf + (size_t)s * QKV_N + (hh < NHEADS ? hh * HD : HID + (hh - NHEADS) * HD);
  int d2 = d1 + 64;
  int ax1 = (d1 < 32) ? 0 : 1;  // sections: [0,32)->ax0, [32,80)->ax1, [80,128)->ax2
  int ax2 = (d2 < 80) ? 1 : 2;
  float c1 = cb[(size_t)ax1 * S_LEN * HD + (size_t)s * HD + d1];
  float s1 = sb[(size_t)ax1 * S_LEN * HD + (size_t)s * HD + d1];
  float c2 = cb[(size_t)ax2 * S_LEN * HD + (size_t)s * HD + d2];
  float s2 = sb[(size_t)ax2 * S_LEN * HD + (size_t)s * HD + d2];
  float x1 = row[d1], x2 = row[d2];
  float y1 = x1 * c1 - x2 * s1;
  float y2 = x2 * c2 + x1 * s2;
  __hip_bfloat16 *dh, *dl;
  size_t base;
  if (hh < NHEADS) { dh = qhi; dl = qlo; base = (size_t)s * HID + hh * HD; }
  else { dh = khi; dl = klo; base = (size_t)s * 512 + (hh - NHEADS) * HD; }
  __hip_bfloat16 h1, l1, h2, l2;
  split2(y1, h1, l1);
  split2(y2, h2, l2);
  dh[base + d1] = h1; dl[base + d1] = l1;
  dh[base + d2] = h2; dl[base + d2] = l2;
}

// ---------------- V transpose from fp32 qkv: vt[j][d][k] ----------------
__global__ void vtrans(const float* __restrict__ qf, __hip_bfloat16* __restrict__ vt) {
  __shared__ __hip_bfloat16 t[64][65];
  const int j = blockIdx.z;
  const int d0 = blockIdx.y * 64;
  const int k0 = blockIdx.x * 64;
  const int tid = threadIdx.x;
#pragma unroll
  for (int half = 0; half < 2; ++half) {
    int r = half * 32 + (tid >> 3);
    int c = (tid & 7) * 8;
    const float* p = qf + (size_t)(k0 + r) * QKV_N + (HID + 512) + j * HD + d0 + c;
    float4 a = ((const float4*)p)[0];
    float4 b = ((const float4*)p)[1];
    t[c + 0][r] = __float2bfloat16(a.x); t[c + 1][r] = __float2bfloat16(a.y);
    t[c + 2][r] = __float2bfloat16(a.z); t[c + 3][r] = __float2bfloat16(a.w);
    t[c + 4][r] = __float2bfloat16(b.x); t[c + 5][r] = __float2bfloat16(b.y);
    t[c + 6][r] = __float2bfloat16(b.z); t[c + 7][r] = __float2bfloat16(b.w);
  }
  __syncthreads();
#pragma unroll
  for (int half = 0; half < 2; ++half) {
    int r = half * 32 + (tid >> 3);
    int c = (tid & 7) * 8;
    __hip_bfloat16 tmp[8];
#pragma unroll
    for (int u = 0; u < 8; ++u) tmp[u] = t[r][c + u];
    *(bf16x8*)&vt[(size_t)j * (HD * S_LEN) + (size_t)(d0 + r) * S_LEN + k0 + c] = *(const bf16x8*)tmp;
  }
}

// ------------- swizzled staging: LDS linear dest, pre-swizzled global src -------------
// 64 rows x 128 cols (16 slots/row of 8 bf16): slot ^= row&7
__device__ __forceinline__ void stageK_sw(__hip_bfloat16* dst, const __hip_bfloat16* gsrc,
                                          int ldg, int tid) {
#pragma unroll
  for (int it = 0; it < 4; ++it) {
    int c = it * 256 + tid;
    int rw = c >> 4, sl = c & 15;
    int gcol = (sl ^ (rw & 7)) << 3;
    gl_lds16(gsrc + (size_t)rw * ldg + gcol, dst + (size_t)(it * 256 + (tid & 192)) * 8);
  }
}
// 128 rows x 64 cols (8 slots/row): slot ^= row&7
__device__ __forceinline__ void stageV_sw(__hip_bfloat16* dst, const __hip_bfloat16* gsrc,
                                          int ldg, int tid) {
#pragma unroll
  for (int it = 0; it < 4; ++it) {
    int c = it * 256 + tid;
    int rw = c >> 3, sl = c & 7;
    int gcol = (sl ^ (rw & 7)) << 3;
    gl_lds16(gsrc + (size_t)rw * ldg + gcol, dst + (size_t)(it * 256 + (tid & 192)) * 8);
  }
}

// ---------------- pass 1: row max + sumexp, 1-term (hi-only) logits ----------------
__global__ __launch_bounds__(256, 2) void attn_stats_lite(
    const __hip_bfloat16* __restrict__ qhi, const __hip_bfloat16* __restrict__ khi,
    float* __restrict__ mbuf, float* __restrict__ lbuf) {
  __shared__ __hip_bfloat16 Kh[64 * 128];  // 16 KB
  const int qb = 31 - blockIdx.x, h = blockIdx.y;
  const int hkv = h / NREP;
  const int tid = threadIdx.x;
  const int lane = tid & 63, w = tid >> 6;
  const int l15 = lane & 15, l4 = lane >> 4;
  const int sw = (l15 & 7);
  bf16x8 qh[4];
  {
    const __hip_bfloat16* qp = qhi + (size_t)(qb * 64 + w * 16 + l15) * HID + h * HD + l4 * 8;
#pragma unroll
    for (int kk = 0; kk < 4; ++kk) qh[kk] = *(const bf16x8*)(qp + kk * 32);
  }
  float m_run[4], l_run[4];
#pragma unroll
  for (int r = 0; r < 4; ++r) { m_run[r] = -1e30f; l_run[r] = 0.f; }
  const int nkt = qb + 1;
  for (int kt = 0; kt < nkt; ++kt) {
    __syncthreads();
    stageK_sw(Kh, khi + (size_t)(kt * 64) * 512 + hkv * HD, 512, tid);
    __syncthreads();
    f32x4 acc[4] = {};
#pragma unroll
    for (int kk = 0; kk < 4; ++kk) {
#pragma unroll
      for (int n = 0; n < 4; ++n) {
        bf16x8 bh = *(const bf16x8*)&Kh[(n * 16 + l15) * 128 + (((kk * 4 + l4) ^ sw) << 3)];
        acc[n] = MFMA_B16(qh[kk], bh, acc[n]);
      }
    }
    const bool diag = (kt == qb);
#pragma unroll
    for (int r = 0; r < 4; ++r) {
      int rowg = qb * 64 + w * 16 + l4 * 4 + r;
      float v[4], tmax = -1e30f;
#pragma unroll
      for (int n = 0; n < 4; ++n) {
        float x = acc[n][r] * SCALE;
        if (diag && (kt * 64 + n * 16 + l15) > rowg) x = -1e30f;
        v[n] = x;
        tmax = fmaxf(tmax, x);
      }
      tmax = fmaxf(tmax, __shfl_xor(tmax, 1));
      tmax = fmaxf(tmax, __shfl_xor(tmax, 2));
      tmax = fmaxf(tmax, __shfl_xor(tmax, 4));
      tmax = fmaxf(tmax, __shfl_xor(tmax, 8));
      float mold = m_run[r];
      float mnew = fmaxf(mold, tmax);
      float sum = 0.f;
#pragma unroll
      for (int n = 0; n < 4; ++n) sum += __expf(v[n] - mnew);
      sum += __shfl_xor(sum, 1);
      sum += __shfl_xor(sum, 2);
      sum += __shfl_xor(sum, 4);
      sum += __shfl_xor(sum, 8);
      l_run[r] = l_run[r] * __expf(mold - mnew) + sum;
      m_run[r] = mnew;
    }
  }
  if (l15 == 0) {
#pragma unroll
    for (int r = 0; r < 4; ++r) {
      int row = qb * 64 + w * 16 + l4 * 4 + r;
      mbuf[h * S_LEN + row] = m_run[r];
      lbuf[h * S_LEN + row] = l_run[r];
    }
  }
}

// ---------------- pass 2: per-key accumulated softmax mass (split logits) ----------------
__global__ __launch_bounds__(256, 2) void attn_scores(
    const __hip_bfloat16* __restrict__ qhi, const __hip_bfloat16* __restrict__ qlo,
    const __hip_bfloat16* __restrict__ khi, const __hip_bfloat16* __restrict__ klo,
    const float* __restrict__ mbuf, const float* __restrict__ lbuf,
    float* __restrict__ scores) {
  __shared__ __hip_bfloat16 Kh[64 * 128], Kl[64 * 128];  // 32 KB
  const int qb = 31 - blockIdx.x, h = blockIdx.y;
  const int hkv = h / NREP;
  const int tid = threadIdx.x;
  const int lane = tid & 63, w = tid >> 6;
  const int l15 = lane & 15, l4 = lane >> 4;
  const int sw = (l15 & 7);
  bf16x8 qh[4], ql[4];
  {
    const size_t qoff = (size_t)(qb * 64 + w * 16 + l15) * HID + h * HD + l4 * 8;
#pragma unroll
    for (int kk = 0; kk < 4; ++kk) {
      qh[kk] = *(const bf16x8*)(qhi + qoff + kk * 32);
      ql[kk] = *(const bf16x8*)(qlo + qoff + kk * 32);
    }
  }
  float mrow[4], invl[4];
#pragma unroll
  for (int r = 0; r < 4; ++r) {
    int row = qb * 64 + w * 16 + l4 * 4 + r;
    mrow[r] = mbuf[h * S_LEN + row];
    invl[r] = 1.0f / lbuf[h * S_LEN + row];
  }
  const int nkt = qb + 1;
  for (int kt = 0; kt < nkt; ++kt) {
    __syncthreads();
    stageK_sw(Kh, khi + (size_t)(kt * 64) * 512 + hkv * HD, 512, tid);
    stageK_sw(Kl, klo + (size_t)(kt * 64) * 512 + hkv * HD, 512, tid);
    __syncthreads();
    f32x4 acc[4] = {};
#pragma unroll
    for (int kk = 0; kk < 4; ++kk) {
#pragma unroll
      for (int n = 0; n < 4; ++n) {
        int off = (n * 16 + l15) * 128 + (((kk * 4 + l4) ^ sw) << 3);
        bf16x8 bh = *(const bf16x8*)&Kh[off];
        bf16x8 bl = *(const bf16x8*)&Kl[off];
        acc[n] = MFMA_B16(qh[kk], bh, acc[n]);
        acc[n] = MFMA_B16(qh[kk], bl, acc[n]);
        acc[n] = MFMA_B16(ql[kk], bh, acc[n]);
      }
    }
    const bool diag = (kt == qb);
    float colsum[4] = {0.f, 0.f, 0.f, 0.f};
#pragma unroll
    for (int r = 0; r < 4; ++r) {
      int rowg = qb * 64 + w * 16 + l4 * 4 + r;
#pragma unroll
      for (int n = 0; n < 4; ++n) {
        float x = acc[n][r] * SCALE;
        if (!(diag && (kt * 64 + n * 16 + l15) > rowg))
          colsum[n] += __expf(x - mrow[r]) * invl[r];
      }
    }
#pragma unroll
    for (int n = 0; n < 4; ++n) {
      colsum[n] += __shfl_xor(colsum[n], 16);
      colsum[n] += __shfl_xor(colsum[n], 32);
    }
    if (lane < 16) {
#pragma unroll
      for (int n = 0; n < 4; ++n)
        atomicAdd(&scores[h * S_LEN + kt * 64 + n * 16 + lane], colsum[n]);
    }
  }
}

// ---------------- pass 3: exact top-k (boundary search) -> keep mask ----------------
__global__ void h2o_topk(const float* __restrict__ scores, unsigned char* __restrict__ keep) {
  const int h = blockIdx.x;
  const int tid = threadIdx.x;
  const int MS = 409, ME = 1844, REGN = 1435, KSEL = 204;
  __shared__ float sv[1435];
  __shared__ int cnt, eqn;
  __shared__ int eqlist[256];
  for (int i = tid; i < REGN; i += 256) sv[i] = scores[h * S_LEN + MS + i];
  for (int i = tid; i < S_LEN; i += 256)
    keep[h * S_LEN + i] = (i < MS || i >= ME) ? 1 : 0;
  __syncthreads();
  unsigned lo = 0u, hi = 0x7f800000u;
  while (hi - lo > 1u) {
    unsigned mid = lo + ((hi - lo) >> 1);
    if (tid == 0) cnt = 0;
    __syncthreads();
    int lc = 0;
    for (int i = tid; i < REGN; i += 256) lc += (__float_as_uint(sv[i]) >= mid) ? 1 : 0;
    if (lc) atomicAdd(&cnt, lc);
    __syncthreads();
    int c = cnt;
    __syncthreads();
    if (c >= KSEL) lo = mid;
    else hi = mid;
  }
  if (tid == 0) { cnt = 0; eqn = 0; }
  __syncthreads();
  int lgt = 0;
  for (int i = tid; i < REGN; i += 256) {
    unsigned b = __float_as_uint(sv[i]);
    if (b > lo) { keep[h * S_LEN + MS + i] = 1; lgt++; }
    else if (b == lo) {
      int p = atomicAdd(&eqn, 1);
      if (p < 256) eqlist[p] = i;
    }
  }
  if (lgt) atomicAdd(&cnt, lgt);
  __syncthreads();
  if (tid == 0) {
    int r = KSEL - cnt;
    int ne = eqn > 256 ? 256 : eqn;
    for (int t = 0; t < r; ++t) {
      int best = 0x7fffffff, bj = -1;
      for (int j = 0; j < ne; ++j)
        if (eqlist[j] < best) { best = eqlist[j]; bj = j; }
      if (bj < 0) break;
      keep[h * S_LEN + MS + best] = 1;
      eqlist[bj] = 0x7fffffff;
    }
  }
}

// ---------------- pass 4: pruned+renormalized attention output (fp16 ctx out) ----------------
__global__ __launch_bounds__(256, 2) void attn_out(
    const __hip_bfloat16* __restrict__ qhi, const __hip_bfloat16* __restrict__ qlo,
    const __hip_bfloat16* __restrict__ khi, const __hip_bfloat16* __restrict__ klo,
    const __hip_bfloat16* __restrict__ vt, const float* __restrict__ mbuf,
    const unsigned char* __restrict__ keep, _Float16* __restrict__ ctx) {
  __shared__ __hip_bfloat16 Kh[64 * 128];   // 16 KB
  __shared__ __hip_bfloat16 Kl[64 * 128];   // 16 KB
  __shared__ __hip_bfloat16 Vtl[128 * 64];  // 16 KB
  __shared__ __hip_bfloat16 Wt[4 * 16 * 64];// 8 KB -> 56 KB total (2 blocks/CU)
  const int qb = 31 - blockIdx.x, h = blockIdx.y;
  const int hkv = h / NREP;
  const int tid = threadIdx.x;
  const int lane = tid & 63, w = tid >> 6;
  const int l15 = lane & 15, l4 = lane >> 4;
  const int sw = (l15 & 7);
  bf16x8 qh[4], ql[4];
  {
    const size_t qoff = (size_t)(qb * 64 + w * 16 + l15) * HID + h * HD + l4 * 8;
#pragma unroll
    for (int kk = 0; kk < 4; ++kk) {
      qh[kk] = *(const bf16x8*)(qhi + qoff + kk * 32);
      ql[kk] = *(const bf16x8*)(qlo + qoff + kk * 32);
    }
  }
  float mrow[4];
#pragma unroll
  for (int r = 0; r < 4; ++r)
    mrow[r] = mbuf[h * S_LEN + qb * 64 + w * 16 + l4 * 4 + r];
  f32x4 o[8] = {};
  float dens[4] = {0.f, 0.f, 0.f, 0.f};
  const int nkt = qb + 1;
  for (int kt = 0; kt < nkt; ++kt) {
    __syncthreads();
    stageK_sw(Kh, khi + (size_t)(kt * 64) * 512 + hkv * HD, 512, tid);
    stageK_sw(Kl, klo + (size_t)(kt * 64) * 512 + hkv * HD, 512, tid);
    stageV_sw(Vtl, vt + (size_t)hkv * (HD * S_LEN) + kt * 64, S_LEN, tid);
    __syncthreads();
    // QK^T 3-term over 64 keys
    f32x4 acc[4] = {};
#pragma unroll
    for (int kk = 0; kk < 4; ++kk) {
#pragma unroll
      for (int n = 0; n < 4; ++n) {
        int off = (n * 16 + l15) * 128 + (((kk * 4 + l4) ^ sw) << 3);
        bf16x8 bh = *(const bf16x8*)&Kh[off];
        bf16x8 bl = *(const bf16x8*)&Kl[off];
        acc[n] = MFMA_B16(qh[kk], bh, acc[n]);
        acc[n] = MFMA_B16(qh[kk], bl, acc[n]);
        acc[n] = MFMA_B16(ql[kk], bh, acc[n]);
      }
    }
    const bool diag = (kt == qb);
    float kf[4];
#pragma unroll
    for (int n = 0; n < 4; ++n)
      kf[n] = (float)keep[h * S_LEN + kt * 64 + n * 16 + l15];
#pragma unroll
    for (int r = 0; r < 4; ++r) {
      int rowg = qb * 64 + w * 16 + l4 * 4 + r;
      int row16 = l4 * 4 + r;
#pragma unroll
      for (int n = 0; n < 4; ++n) {
        int coll = n * 16 + l15;
        float wv = 0.f;
        if (!diag || (kt * 64 + coll) <= rowg)
          wv = kf[n] * __expf(acc[n][r] * SCALE - mrow[r]);
        dens[r] += wv;
        Wt[w * 1024 + row16 * 64 + (coll ^ ((row16 & 7) << 3))] = __float2bfloat16(wv);
      }
    }
    // PV: o[n] += W(16x64) * Vt(row=d)
#pragma unroll
    for (int kk = 0; kk < 2; ++kk) {
      bf16x8 af = *(const bf16x8*)&Wt[w * 1024 + l15 * 64 + ((kk * 32 + l4 * 8) ^ (sw << 3))];
#pragma unroll
      for (int n = 0; n < 8; ++n) {
        bf16x8 bf = *(const bf16x8*)&Vtl[(n * 16 + l15) * 64 + (((kk * 4 + l4) ^ sw) << 3)];
        o[n] = MFMA_B16(af, bf, o[n]);
      }
    }
  }
  float invd[4];
#pragma unroll
  for (int r = 0; r < 4; ++r) {
    float d = dens[r];
    d += __shfl_xor(d, 1);
    d += __shfl_xor(d, 2);
    d += __shfl_xor(d, 4);
    d += __shfl_xor(d, 8);
    invd[r] = 1.0f / fmaxf(d, 1e-20f);
  }
#pragma unroll
  for (int n = 0; n < 8; ++n)
#pragma unroll
    for (int r = 0; r < 4; ++r) {
      size_t row = qb * 64 + w * 16 + l4 * 4 + r;
      size_t col = h * HD + n * 16 + l15;
      ctx[row * HID + col] = (_Float16)(o[n][r] * invd[r]);
    }
}

// ---------------- host glue ----------------
extern "C" void kernel_launch(void* const* d_in, const int* in_sizes, int n_in,
                              void* d_out, int out_size, void* d_ws, size_t ws_size,
                              hipStream_t stream) {
  const float* hidden = (const float*)d_in[0];
  const float* cosb = (const float*)d_in[2];
  const float* sinb = (const float*)d_in[3];
  const float* q_w = (const float*)d_in[4];
  const float* q_b = (const float*)d_in[5];
  const float* k_w = (const float*)d_in[6];
  const float* k_b = (const float*)d_in[7];
  const float* v_w = (const float*)d_in[8];
  const float* v_b = (const float*)d_in[9];
  const float* o_w = (const float*)d_in[10];

  char* ws = (char*)d_ws;
  // Phase A (QKV GEMM):
  float* qkv_f32 = (float*)(ws + 0);                        // 37,748,736
  _Float16* hf16 = (_Float16*)(ws + 37748736);              // 14,680,064 -> 52,428,800
  _Float16* wqkv16 = (_Float16*)(ws + 52428800);            // 33,030,144 -> 85,458,944
  float* biasb = (float*)(ws + 85458944);                   //     18,432 -> 85,477,376
  // Phase B overlays:
  __hip_bfloat16* qhi = (__hip_bfloat16*)(ws + 37748736);   // 14,680,064 (over dead hf16)
  _Float16* wo16 = (_Float16*)(ws + 52428800);              // 25,690,112 (over dead wqkv16)
  __hip_bfloat16* qlo = (__hip_bfloat16*)(ws + 85477376);   // 14,680,064 -> 100,157,440
  __hip_bfloat16* khi = (__hip_bfloat16*)(ws + 100157440);  //  2,097,152
  __hip_bfloat16* klo = (__hip_bfloat16*)(ws + 102254592);  //  2,097,152
  __hip_bfloat16* vt = (__hip_bfloat16*)(ws + 104351744);   //  2,097,152
  float* mbuf = (float*)(ws + 106448896);                   //    229,376
  float* lbuf = (float*)(ws + 106678272);                   //    229,376
  float* scores = (float*)(ws + 106907648);                 //    229,376
  unsigned char* keep = (unsigned char*)(ws + 107137024);   //     57,344 -> 107,194,368 peak
  // Phase C overlay (qkv_f32 dead after rope+vtrans):
  _Float16* ctx16 = (_Float16*)(ws + 0);                    // 14,680,064

  hipMemcpyAsync(biasb, q_b, 3584 * 4, hipMemcpyDeviceToDevice, stream);
  hipMemcpyAsync(biasb + 3584, k_b, 512 * 4, hipMemcpyDeviceToDevice, stream);
  hipMemcpyAsync(biasb + 4096, v_b, 512 * 4, hipMemcpyDeviceToDevice, stream);

  // fp16 operand conversion
  cvt_f32_f16<<<7168, 256, 0, stream>>>(hidden, hf16, 1835008);
  cvt_f32_f16<<<12544, 256, 0, stream>>>(q_w, wqkv16, 3211264);
  cvt_f32_f16<<<1792, 256, 0, stream>>>(k_w, wqkv16 + (size_t)3584 * 3584, 458752);
  cvt_f32_f16<<<1792, 256, 0, stream>>>(v_w, wqkv16 + (size_t)4096 * 3584, 458752);

  // QKV projection (fp16 MFMA, fp32 accum, +bias)
  gemm_f16<true><<<dim3(36, 16), 256, 0, stream>>>(hf16, HID, wqkv16, HID,
                                                   biasb, qkv_f32, QKV_N, HID);

  // o_w conversion into now-dead wqkv space (stream-ordered)
  cvt_f32_f16<<<12544, 256, 0, stream>>>(o_w, wo16, 3211264);

  rope_split<<<16384, 256, 0, stream>>>(qkv_f32, cosb, sinb, qhi, qlo, khi, klo);
  vtrans<<<dim3(32, 2, 4), 256, 0, stream>>>(qkv_f32, vt);
  hipMemsetAsync(scores, 0, NHEADS * S_LEN * 4, stream);

  attn_stats_lite<<<dim3(32, 28), 256, 0, stream>>>(qhi, khi, mbuf, lbuf);
  attn_scores<<<dim3(32, 28), 256, 0, stream>>>(qhi, qlo, khi, klo, mbuf, lbuf, scores);
  h2o_topk<<<28, 256, 0, stream>>>(scores, keep);
  attn_out<<<dim3(32, 28), 256, 0, stream>>>(qhi, qlo, khi, klo, vt, mbuf, keep, ctx16);

  // output projection (fp16 MFMA, fp32 accum)
  gemm_f16<false><<<dim3(28, 16), 256, 0, stream>>>(ctx16, HID, wo16, HID,
                                                    nullptr, (float*)d_out, HID, HID);
}

// Round 8
// 540.608 us; speedup vs baseline: 3.1815x; 1.2259x over previous
//
#include <hip/hip_runtime.h>
#include <hip/hip_bf16.h>
#include <stdint.h>

#define S_LEN 2048
#define HID 3584
#define NHEADS 28
#define KVHEADS 4
#define HD 128
#define QKV_N 4608
#define NREP 7
#define SCALE 0.08838834764831845f

typedef __attribute__((ext_vector_type(8))) short bf16x8;
typedef __attribute__((ext_vector_type(8))) _Float16 f16x8;
typedef __attribute__((ext_vector_type(4))) float f32x4;

#define MFMA_B16(a, b, c) __builtin_amdgcn_mfma_f32_16x16x32_bf16((a), (b), (c), 0, 0, 0)
#define MFMA_F16(a, b, c) __builtin_amdgcn_mfma_f32_16x16x32_f16((a), (b), (c), 0, 0, 0)

__device__ __forceinline__ void gl_lds16(const void* g, void* l) {
  __builtin_amdgcn_global_load_lds(
      (__attribute__((address_space(1))) void*)(void*)(g),
      (__attribute__((address_space(3))) void*)(l), 16, 0, 0);
}

// ---------------- fp32 -> fp16 conversion ----------------
__global__ void cvt_f32_f16(const float* __restrict__ src, _Float16* __restrict__ dst, int n4) {
  int i = blockIdx.x * 256 + threadIdx.x;
  if (i >= n4) return;
  float4 v = ((const float4*)src)[i];
  _Float16 t[4] = {(_Float16)v.x, (_Float16)v.y, (_Float16)v.z, (_Float16)v.w};
  ((uint2*)dst)[i] = *(const uint2*)t;
}

// ---------------- fp16 GEMM: C = A * B^T (+bias), m97 structure ----------------
template <bool HAS_BIAS>
__global__ __launch_bounds__(256, 2) void gemm_f16(
    const _Float16* __restrict__ A, int lda,
    const _Float16* __restrict__ B, int ldb,
    const float* __restrict__ bias, float* __restrict__ C, int ldc, int K) {
  __shared__ _Float16 lA[128 * 32], lB[128 * 32];
  const int tid = threadIdx.x;
  const int lane = tid & 63;
  const int wid = tid >> 6;
  const int wr = wid >> 1, wc = wid & 1;
  const int l15 = lane & 15, l4 = lane >> 4;
  const int bm = blockIdx.y * 128, bn = blockIdx.x * 128;
  f32x4 acc[4][4] = {};
  for (int k0 = 0; k0 < K; k0 += 32) {
    __syncthreads();
#pragma unroll
    for (int it = 0; it < 2; ++it) {
      int c = it * 256 + tid;
      int row = c >> 2, col = (c & 3) << 3;
      int lo = (it * 256 + (tid & 192)) * 8;
      gl_lds16(A + (size_t)(bm + row) * lda + (k0 + col), &lA[lo]);
      gl_lds16(B + (size_t)(bn + row) * ldb + (k0 + col), &lB[lo]);
    }
    __syncthreads();
    f16x8 af[4], bf[4];
#pragma unroll
    for (int m = 0; m < 4; ++m)
      af[m] = *(const f16x8*)&lA[(wr * 64 + m * 16 + l15) * 32 + l4 * 8];
#pragma unroll
    for (int n = 0; n < 4; ++n)
      bf[n] = *(const f16x8*)&lB[(wc * 64 + n * 16 + l15) * 32 + l4 * 8];
#pragma unroll
    for (int m = 0; m < 4; ++m)
#pragma unroll
      for (int n = 0; n < 4; ++n)
        acc[m][n] = MFMA_F16(af[m], bf[n], acc[m][n]);
  }
#pragma unroll
  for (int m = 0; m < 4; ++m)
#pragma unroll
    for (int n = 0; n < 4; ++n)
#pragma unroll
      for (int r = 0; r < 4; ++r) {
        size_t row = bm + wr * 64 + m * 16 + l4 * 4 + r;
        size_t col = bn + wc * 64 + n * 16 + l15;
        float v = acc[m][n][r];
        if (HAS_BIAS) v += bias[col];
        C[row * ldc + col] = v;
      }
}

// ---------------- rope on fp32 qkv, emit fp16 Q/K ----------------
__global__ void rope_f16(const float* __restrict__ qf, const float* __restrict__ cb,
                         const float* __restrict__ sb,
                         _Float16* __restrict__ q16, _Float16* __restrict__ k16) {
  int idx = blockIdx.x * 256 + threadIdx.x;  // 2048 * 32 * 64
  int d1 = idx & 63;
  int hh = (idx >> 6) & 31;
  int s = idx >> 11;
  if (s >= S_LEN) return;
  const float* row = qf + (size_t)s * QKV_N + (hh < NHEADS ? hh * HD : HID + (hh - NHEADS) * HD);
  int d2 = d1 + 64;
  int ax1 = (d1 < 32) ? 0 : 1;  // sections: [0,32)->ax0, [32,80)->ax1, [80,128)->ax2
  int ax2 = (d2 < 80) ? 1 : 2;
  float c1 = cb[(size_t)ax1 * S_LEN * HD + (size_t)s * HD + d1];
  float s1 = sb[(size_t)ax1 * S_LEN * HD + (size_t)s * HD + d1];
  float c2 = cb[(size_t)ax2 * S_LEN * HD + (size_t)s * HD + d2];
  float s2 = sb[(size_t)ax2 * S_LEN * HD + (size_t)s * HD + d2];
  float x1 = row[d1], x2 = row[d2];
  float y1 = x1 * c1 - x2 * s1;
  float y2 = x2 * c2 + x1 * s2;
  _Float16* dp;
  size_t base;
  if (hh < NHEADS) { dp = q16; base = (size_t)s * HID + hh * HD; }
  else { dp = k16; base = (size_t)s * 512 + (hh - NHEADS) * HD; }
  dp[base + d1] = (_Float16)y1;
  dp[base + d2] = (_Float16)y2;
}

// ---------------- V transpose from fp32 qkv: vt[j][d][k] (bf16) ----------------
__global__ void vtrans(const float* __restrict__ qf, __hip_bfloat16* __restrict__ vt) {
  __shared__ __hip_bfloat16 t[64][65];
  const int j = blockIdx.z;
  const int d0 = blockIdx.y * 64;
  const int k0 = blockIdx.x * 64;
  const int tid = threadIdx.x;
#pragma unroll
  for (int half = 0; half < 2; ++half) {
    int r = half * 32 + (tid >> 3);
    int c = (tid & 7) * 8;
    const float* p = qf + (size_t)(k0 + r) * QKV_N + (HID + 512) + j * HD + d0 + c;
    float4 a = ((const float4*)p)[0];
    float4 b = ((const float4*)p)[1];
    t[c + 0][r] = __float2bfloat16(a.x); t[c + 1][r] = __float2bfloat16(a.y);
    t[c + 2][r] = __float2bfloat16(a.z); t[c + 3][r] = __float2bfloat16(a.w);
    t[c + 4][r] = __float2bfloat16(b.x); t[c + 5][r] = __float2bfloat16(b.y);
    t[c + 6][r] = __float2bfloat16(b.z); t[c + 7][r] = __float2bfloat16(b.w);
  }
  __syncthreads();
#pragma unroll
  for (int half = 0; half < 2; ++half) {
    int r = half * 32 + (tid >> 3);
    int c = (tid & 7) * 8;
    __hip_bfloat16 tmp[8];
#pragma unroll
    for (int u = 0; u < 8; ++u) tmp[u] = t[r][c + u];
    *(bf16x8*)&vt[(size_t)j * (HD * S_LEN) + (size_t)(d0 + r) * S_LEN + k0 + c] = *(const bf16x8*)tmp;
  }
}

// ------------- swizzled staging: LDS linear dest, pre-swizzled global src -------------
// 64 rows x 128 cols of 2-byte elems (16 slots/row of 8): slot ^= row&7
template <typename T>
__device__ __forceinline__ void stageK_sw(T* dst, const T* gsrc, int ldg, int tid) {
#pragma unroll
  for (int it = 0; it < 4; ++it) {
    int c = it * 256 + tid;
    int rw = c >> 4, sl = c & 15;
    int gcol = (sl ^ (rw & 7)) << 3;
    gl_lds16(gsrc + (size_t)rw * ldg + gcol, dst + (size_t)(it * 256 + (tid & 192)) * 8);
  }
}
// 128 rows x 64 cols (8 slots/row): slot ^= row&7
__device__ __forceinline__ void stageV_sw(__hip_bfloat16* dst, const __hip_bfloat16* gsrc,
                                          int ldg, int tid) {
#pragma unroll
  for (int it = 0; it < 4; ++it) {
    int c = it * 256 + tid;
    int rw = c >> 3, sl = c & 7;
    int gcol = (sl ^ (rw & 7)) << 3;
    gl_lds16(gsrc + (size_t)rw * ldg + gcol, dst + (size_t)(it * 256 + (tid & 192)) * 8);
  }
}

// ---------------- pass 1: row sumexp with m=0 (logits bounded; fp16 QK) ----------------
__global__ __launch_bounds__(256, 4) void attn_l(
    const _Float16* __restrict__ q16, const _Float16* __restrict__ k16,
    float* __restrict__ lbuf) {
  __shared__ _Float16 Kh[64 * 128];  // 16 KB
  const int qb = 31 - blockIdx.x, h = blockIdx.y;
  const int hkv = h / NREP;
  const int tid = threadIdx.x;
  const int lane = tid & 63, w = tid >> 6;
  const int l15 = lane & 15, l4 = lane >> 4;
  const int sw = (l15 & 7);
  f16x8 qh[4];
  {
    const _Float16* qp = q16 + (size_t)(qb * 64 + w * 16 + l15) * HID + h * HD + l4 * 8;
#pragma unroll
    for (int kk = 0; kk < 4; ++kk) qh[kk] = *(const f16x8*)(qp + kk * 32);
  }
  float lsum[4] = {0.f, 0.f, 0.f, 0.f};
  const int nkt = qb + 1;
  for (int kt = 0; kt < nkt; ++kt) {
    __syncthreads();
    stageK_sw(Kh, k16 + (size_t)(kt * 64) * 512 + hkv * HD, 512, tid);
    __syncthreads();
    f32x4 acc[4] = {};
#pragma unroll
    for (int kk = 0; kk < 4; ++kk) {
#pragma unroll
      for (int n = 0; n < 4; ++n) {
        f16x8 bh = *(const f16x8*)&Kh[(n * 16 + l15) * 128 + (((kk * 4 + l4) ^ sw) << 3)];
        acc[n] = MFMA_F16(qh[kk], bh, acc[n]);
      }
    }
    const bool diag = (kt == qb);
#pragma unroll
    for (int r = 0; r < 4; ++r) {
      int rowg = qb * 64 + w * 16 + l4 * 4 + r;
#pragma unroll
      for (int n = 0; n < 4; ++n) {
        if (!(diag && (kt * 64 + n * 16 + l15) > rowg))
          lsum[r] += __expf(acc[n][r] * SCALE);
      }
    }
  }
#pragma unroll
  for (int r = 0; r < 4; ++r) {
    lsum[r] += __shfl_xor(lsum[r], 1);
    lsum[r] += __shfl_xor(lsum[r], 2);
    lsum[r] += __shfl_xor(lsum[r], 4);
    lsum[r] += __shfl_xor(lsum[r], 8);
  }
  if (l15 == 0) {
#pragma unroll
    for (int r = 0; r < 4; ++r)
      lbuf[h * S_LEN + qb * 64 + w * 16 + l4 * 4 + r] = lsum[r];
  }
}

// ---------------- pass 2: per-key accumulated softmax mass (fp16 QK) ----------------
__global__ __launch_bounds__(256, 4) void attn_scores(
    const _Float16* __restrict__ q16, const _Float16* __restrict__ k16,
    const float* __restrict__ lbuf, float* __restrict__ scores) {
  __shared__ _Float16 Kh[64 * 128];  // 16 KB
  const int qb = 31 - blockIdx.x, h = blockIdx.y;
  const int hkv = h / NREP;
  const int tid = threadIdx.x;
  const int lane = tid & 63, w = tid >> 6;
  const int l15 = lane & 15, l4 = lane >> 4;
  const int sw = (l15 & 7);
  f16x8 qh[4];
  {
    const _Float16* qp = q16 + (size_t)(qb * 64 + w * 16 + l15) * HID + h * HD + l4 * 8;
#pragma unroll
    for (int kk = 0; kk < 4; ++kk) qh[kk] = *(const f16x8*)(qp + kk * 32);
  }
  float invl[4];
#pragma unroll
  for (int r = 0; r < 4; ++r)
    invl[r] = 1.0f / lbuf[h * S_LEN + qb * 64 + w * 16 + l4 * 4 + r];
  const int nkt = qb + 1;
  for (int kt = 0; kt < nkt; ++kt) {
    __syncthreads();
    stageK_sw(Kh, k16 + (size_t)(kt * 64) * 512 + hkv * HD, 512, tid);
    __syncthreads();
    f32x4 acc[4] = {};
#pragma unroll
    for (int kk = 0; kk < 4; ++kk) {
#pragma unroll
      for (int n = 0; n < 4; ++n) {
        f16x8 bh = *(const f16x8*)&Kh[(n * 16 + l15) * 128 + (((kk * 4 + l4) ^ sw) << 3)];
        acc[n] = MFMA_F16(qh[kk], bh, acc[n]);
      }
    }
    const bool diag = (kt == qb);
    float colsum[4] = {0.f, 0.f, 0.f, 0.f};
#pragma unroll
    for (int r = 0; r < 4; ++r) {
      int rowg = qb * 64 + w * 16 + l4 * 4 + r;
#pragma unroll
      for (int n = 0; n < 4; ++n) {
        if (!(diag && (kt * 64 + n * 16 + l15) > rowg))
          colsum[n] += __expf(acc[n][r] * SCALE) * invl[r];
      }
    }
#pragma unroll
    for (int n = 0; n < 4; ++n) {
      colsum[n] += __shfl_xor(colsum[n], 16);
      colsum[n] += __shfl_xor(colsum[n], 32);
    }
    if (lane < 16) {
#pragma unroll
      for (int n = 0; n < 4; ++n)
        atomicAdd(&scores[h * S_LEN + kt * 64 + n * 16 + lane], colsum[n]);
    }
  }
}

// ---------------- pass 3: exact top-k (boundary search) -> keep mask ----------------
__global__ void h2o_topk(const float* __restrict__ scores, unsigned char* __restrict__ keep) {
  const int h = blockIdx.x;
  const int tid = threadIdx.x;
  const int MS = 409, ME = 1844, REGN = 1435, KSEL = 204;
  __shared__ float sv[1435];
  __shared__ int cnt, eqn;
  __shared__ int eqlist[256];
  for (int i = tid; i < REGN; i += 256) sv[i] = scores[h * S_LEN + MS + i];
  for (int i = tid; i < S_LEN; i += 256)
    keep[h * S_LEN + i] = (i < MS || i >= ME) ? 1 : 0;
  __syncthreads();
  unsigned lo = 0u, hi = 0x7f800000u;
  while (hi - lo > 1u) {
    unsigned mid = lo + ((hi - lo) >> 1);
    if (tid == 0) cnt = 0;
    __syncthreads();
    int lc = 0;
    for (int i = tid; i < REGN; i += 256) lc += (__float_as_uint(sv[i]) >= mid) ? 1 : 0;
    if (lc) atomicAdd(&cnt, lc);
    __syncthreads();
    int c = cnt;
    __syncthreads();
    if (c >= KSEL) lo = mid;
    else hi = mid;
  }
  if (tid == 0) { cnt = 0; eqn = 0; }
  __syncthreads();
  int lgt = 0;
  for (int i = tid; i < REGN; i += 256) {
    unsigned b = __float_as_uint(sv[i]);
    if (b > lo) { keep[h * S_LEN + MS + i] = 1; lgt++; }
    else if (b == lo) {
      int p = atomicAdd(&eqn, 1);
      if (p < 256) eqlist[p] = i;
    }
  }
  if (lgt) atomicAdd(&cnt, lgt);
  __syncthreads();
  if (tid == 0) {
    int r = KSEL - cnt;
    int ne = eqn > 256 ? 256 : eqn;
    for (int t = 0; t < r; ++t) {
      int best = 0x7fffffff, bj = -1;
      for (int j = 0; j < ne; ++j)
        if (eqlist[j] < best) { best = eqlist[j]; bj = j; }
      if (bj < 0) break;
      keep[h * S_LEN + MS + best] = 1;
      eqlist[bj] = 0x7fffffff;
    }
  }
}

// ---------------- pass 4: pruned+renormalized attention output (m=0, fp16 QK) ----------------
__global__ __launch_bounds__(256, 4) void attn_out(
    const _Float16* __restrict__ q16, const _Float16* __restrict__ k16,
    const __hip_bfloat16* __restrict__ vt, const unsigned char* __restrict__ keep,
    _Float16* __restrict__ ctx) {
  __shared__ _Float16 Kh[64 * 128];          // 16 KB
  __shared__ __hip_bfloat16 Vtl[128 * 64];   // 16 KB
  __shared__ __hip_bfloat16 Wt[4 * 16 * 64]; // 8 KB -> 40 KB total (4 blocks/CU)
  const int qb = 31 - blockIdx.x, h = blockIdx.y;
  const int hkv = h / NREP;
  const int tid = threadIdx.x;
  const int lane = tid & 63, w = tid >> 6;
  const int l15 = lane & 15, l4 = lane >> 4;
  const int sw = (l15 & 7);
  f16x8 qh[4];
  {
    const _Float16* qp = q16 + (size_t)(qb * 64 + w * 16 + l15) * HID + h * HD + l4 * 8;
#pragma unroll
    for (int kk = 0; kk < 4; ++kk) qh[kk] = *(const f16x8*)(qp + kk * 32);
  }
  f32x4 o[8] = {};
  float dens[4] = {0.f, 0.f, 0.f, 0.f};
  const int nkt = qb + 1;
  for (int kt = 0; kt < nkt; ++kt) {
    __syncthreads();
    stageK_sw(Kh, k16 + (size_t)(kt * 64) * 512 + hkv * HD, 512, tid);
    stageV_sw(Vtl, vt + (size_t)hkv * (HD * S_LEN) + kt * 64, S_LEN, tid);
    __syncthreads();
    f32x4 acc[4] = {};
#pragma unroll
    for (int kk = 0; kk < 4; ++kk) {
#pragma unroll
      for (int n = 0; n < 4; ++n) {
        f16x8 bh = *(const f16x8*)&Kh[(n * 16 + l15) * 128 + (((kk * 4 + l4) ^ sw) << 3)];
        acc[n] = MFMA_F16(qh[kk], bh, acc[n]);
      }
    }
    const bool diag = (kt == qb);
    float kf[4];
#pragma unroll
    for (int n = 0; n < 4; ++n)
      kf[n] = (float)keep[h * S_LEN + kt * 64 + n * 16 + l15];
#pragma unroll
    for (int r = 0; r < 4; ++r) {
      int rowg = qb * 64 + w * 16 + l4 * 4 + r;
      int row16 = l4 * 4 + r;
#pragma unroll
      for (int n = 0; n < 4; ++n) {
        int coll = n * 16 + l15;
        float wv = 0.f;
        if (!diag || (kt * 64 + coll) <= rowg)
          wv = kf[n] * __expf(acc[n][r] * SCALE);
        dens[r] += wv;
        Wt[w * 1024 + row16 * 64 + (coll ^ ((row16 & 7) << 3))] = __float2bfloat16(wv);
      }
    }
    // PV: o[n] += W(16x64) * Vt(row=d)
#pragma unroll
    for (int kk = 0; kk < 2; ++kk) {
      bf16x8 af = *(const bf16x8*)&Wt[w * 1024 + l15 * 64 + ((kk * 32 + l4 * 8) ^ (sw << 3))];
#pragma unroll
      for (int n = 0; n < 8; ++n) {
        bf16x8 bf = *(const bf16x8*)&Vtl[(n * 16 + l15) * 64 + (((kk * 4 + l4) ^ sw) << 3)];
        o[n] = MFMA_B16(af, bf, o[n]);
      }
    }
  }
  float invd[4];
#pragma unroll
  for (int r = 0; r < 4; ++r) {
    float d = dens[r];
    d += __shfl_xor(d, 1);
    d += __shfl_xor(d, 2);
    d += __shfl_xor(d, 4);
    d += __shfl_xor(d, 8);
    invd[r] = 1.0f / fmaxf(d, 1e-30f);
  }
#pragma unroll
  for (int n = 0; n < 8; ++n)
#pragma unroll
    for (int r = 0; r < 4; ++r) {
      size_t row = qb * 64 + w * 16 + l4 * 4 + r;
      size_t col = h * HD + n * 16 + l15;
      ctx[row * HID + col] = (_Float16)(o[n][r] * invd[r]);
    }
}

// ---------------- host glue ----------------
extern "C" void kernel_launch(void* const* d_in, const int* in_sizes, int n_in,
                              void* d_out, int out_size, void* d_ws, size_t ws_size,
                              hipStream_t stream) {
  const float* hidden = (const float*)d_in[0];
  const float* cosb = (const float*)d_in[2];
  const float* sinb = (const float*)d_in[3];
  const float* q_w = (const float*)d_in[4];
  const float* q_b = (const float*)d_in[5];
  const float* k_w = (const float*)d_in[6];
  const float* k_b = (const float*)d_in[7];
  const float* v_w = (const float*)d_in[8];
  const float* v_b = (const float*)d_in[9];
  const float* o_w = (const float*)d_in[10];

  char* ws = (char*)d_ws;
  // Phase A (QKV GEMM):
  float* qkv_f32 = (float*)(ws + 0);                        // 37,748,736
  _Float16* hf16 = (_Float16*)(ws + 37748736);              // 14,680,064 -> 52,428,800
  _Float16* wqkv16 = (_Float16*)(ws + 52428800);            // 33,030,144 -> 85,458,944
  float* biasb = (float*)(ws + 85458944);                   //     18,432 -> 85,477,376
  // Phase B overlays:
  _Float16* q16 = (_Float16*)(ws + 37748736);               // 14,680,064 (over dead hf16)
  _Float16* wo16 = (_Float16*)(ws + 52428800);              // 25,690,112 (over dead wqkv16)
  _Float16* k16 = (_Float16*)(ws + 85477376);               //  2,097,152 -> 87,574,528
  __hip_bfloat16* vt = (__hip_bfloat16*)(ws + 87574528);    //  2,097,152 -> 89,671,680
  float* lbuf = (float*)(ws + 89671680);                    //    229,376 -> 89,901,056
  float* scores = (float*)(ws + 89901056);                  //    229,376 -> 90,130,432
  unsigned char* keep = (unsigned char*)(ws + 90130432);    //     57,344 -> 90,187,776 peak
  // Phase C overlay (qkv_f32 dead after rope+vtrans):
  _Float16* ctx16 = (_Float16*)(ws + 0);                    // 14,680,064

  hipMemcpyAsync(biasb, q_b, 3584 * 4, hipMemcpyDeviceToDevice, stream);
  hipMemcpyAsync(biasb + 3584, k_b, 512 * 4, hipMemcpyDeviceToDevice, stream);
  hipMemcpyAsync(biasb + 4096, v_b, 512 * 4, hipMemcpyDeviceToDevice, stream);

  // fp16 operand conversion
  cvt_f32_f16<<<7168, 256, 0, stream>>>(hidden, hf16, 1835008);
  cvt_f32_f16<<<12544, 256, 0, stream>>>(q_w, wqkv16, 3211264);
  cvt_f32_f16<<<1792, 256, 0, stream>>>(k_w, wqkv16 + (size_t)3584 * 3584, 458752);
  cvt_f32_f16<<<1792, 256, 0, stream>>>(v_w, wqkv16 + (size_t)4096 * 3584, 458752);

  // QKV projection (fp16 MFMA, fp32 accum, +bias)
  gemm_f16<true><<<dim3(36, 16), 256, 0, stream>>>(hf16, HID, wqkv16, HID,
                                                   biasb, qkv_f32, QKV_N, HID);

  // o_w conversion into now-dead wqkv space (stream-ordered)
  cvt_f32_f16<<<12544, 256, 0, stream>>>(o_w, wo16, 3211264);

  rope_f16<<<16384, 256, 0, stream>>>(qkv_f32, cosb, sinb, q16, k16);
  vtrans<<<dim3(32, 2, 4), 256, 0, stream>>>(qkv_f32, vt);
  hipMemsetAsync(scores, 0, NHEADS * S_LEN * 4, stream);

  attn_l<<<dim3(32, 28), 256, 0, stream>>>(q16, k16, lbuf);
  attn_scores<<<dim3(32, 28), 256, 0, stream>>>(q16, k16, lbuf, scores);
  h2o_topk<<<28, 256, 0, stream>>>(scores, keep);
  attn_out<<<dim3(32, 28), 256, 0, stream>>>(q16, k16, vt, keep, ctx16);

  // output projection (fp16 MFMA, fp32 accum)
  gemm_f16<false><<<dim3(28, 16), 256, 0, stream>>>(ctx16, HID, wo16, HID,
                                                    nullptr, (float*)d_out, HID, HID);
}

// Round 9
// 458.821 us; speedup vs baseline: 3.7486x; 1.1783x over previous
//
#include <hip/hip_runtime.h>
#include <hip/hip_bf16.h>
#include <stdint.h>

#define S_LEN 2048
#define HID 3584
#define NHEADS 28
#define KVHEADS 4
#define HD 128
#define QKV_N 4608
#define NREP 7
#define SCALE 0.08838834764831845f
#define NJOBS 896

typedef __attribute__((ext_vector_type(8))) short bf16x8;
typedef __attribute__((ext_vector_type(8))) _Float16 f16x8;
typedef __attribute__((ext_vector_type(4))) float f32x4;

#define MFMA_B16(a, b, c) __builtin_amdgcn_mfma_f32_16x16x32_bf16((a), (b), (c), 0, 0, 0)
#define MFMA_F16(a, b, c) __builtin_amdgcn_mfma_f32_16x16x32_f16((a), (b), (c), 0, 0, 0)

__device__ __forceinline__ void gl_lds16(const void* g, void* l) {
  __builtin_amdgcn_global_load_lds(
      (__attribute__((address_space(1))) void*)(void*)(g),
      (__attribute__((address_space(3))) void*)(l), 16, 0, 0);
}

// ---------------- fp32 -> fp16 conversion ----------------
__global__ void cvt_f32_f16(const float* __restrict__ src, _Float16* __restrict__ dst, int n4) {
  int i = blockIdx.x * 256 + threadIdx.x;
  if (i >= n4) return;
  float4 v = ((const float4*)src)[i];
  _Float16 t[4] = {(_Float16)v.x, (_Float16)v.y, (_Float16)v.z, (_Float16)v.w};
  ((uint2*)dst)[i] = *(const uint2*)t;
}

// ---------------- fp16 GEMM: C = A * B^T (+bias), m97 structure ----------------
template <bool HAS_BIAS>
__global__ __launch_bounds__(256, 2) void gemm_f16(
    const _Float16* __restrict__ A, int lda,
    const _Float16* __restrict__ B, int ldb,
    const float* __restrict__ bias, float* __restrict__ C, int ldc, int K) {
  __shared__ _Float16 lA[128 * 32], lB[128 * 32];
  const int tid = threadIdx.x;
  const int lane = tid & 63;
  const int wid = tid >> 6;
  const int wr = wid >> 1, wc = wid & 1;
  const int l15 = lane & 15, l4 = lane >> 4;
  const int bm = blockIdx.y * 128, bn = blockIdx.x * 128;
  f32x4 acc[4][4] = {};
  for (int k0 = 0; k0 < K; k0 += 32) {
    __syncthreads();
#pragma unroll
    for (int it = 0; it < 2; ++it) {
      int c = it * 256 + tid;
      int row = c >> 2, col = (c & 3) << 3;
      int lo = (it * 256 + (tid & 192)) * 8;
      gl_lds16(A + (size_t)(bm + row) * lda + (k0 + col), &lA[lo]);
      gl_lds16(B + (size_t)(bn + row) * ldb + (k0 + col), &lB[lo]);
    }
    __syncthreads();
    f16x8 af[4], bf[4];
#pragma unroll
    for (int m = 0; m < 4; ++m)
      af[m] = *(const f16x8*)&lA[(wr * 64 + m * 16 + l15) * 32 + l4 * 8];
#pragma unroll
    for (int n = 0; n < 4; ++n)
      bf[n] = *(const f16x8*)&lB[(wc * 64 + n * 16 + l15) * 32 + l4 * 8];
#pragma unroll
    for (int m = 0; m < 4; ++m)
#pragma unroll
      for (int n = 0; n < 4; ++n)
        acc[m][n] = MFMA_F16(af[m], bf[n], acc[m][n]);
  }
#pragma unroll
  for (int m = 0; m < 4; ++m)
#pragma unroll
    for (int n = 0; n < 4; ++n)
#pragma unroll
      for (int r = 0; r < 4; ++r) {
        size_t row = bm + wr * 64 + m * 16 + l4 * 4 + r;
        size_t col = bn + wc * 64 + n * 16 + l15;
        float v = acc[m][n][r];
        if (HAS_BIAS) v += bias[col];
        C[row * ldc + col] = v;
      }
}

// ---------------- rope on fp32 qkv, emit fp16 Q/K ----------------
__global__ void rope_f16(const float* __restrict__ qf, const float* __restrict__ cb,
                         const float* __restrict__ sb,
                         _Float16* __restrict__ q16, _Float16* __restrict__ k16) {
  int idx = blockIdx.x * 256 + threadIdx.x;  // 2048 * 32 * 64
  int d1 = idx & 63;
  int hh = (idx >> 6) & 31;
  int s = idx >> 11;
  if (s >= S_LEN) return;
  const float* row = qf + (size_t)s * QKV_N + (hh < NHEADS ? hh * HD : HID + (hh - NHEADS) * HD);
  int d2 = d1 + 64;
  int ax1 = (d1 < 32) ? 0 : 1;  // sections: [0,32)->ax0, [32,80)->ax1, [80,128)->ax2
  int ax2 = (d2 < 80) ? 1 : 2;
  float c1 = cb[(size_t)ax1 * S_LEN * HD + (size_t)s * HD + d1];
  float s1 = sb[(size_t)ax1 * S_LEN * HD + (size_t)s * HD + d1];
  float c2 = cb[(size_t)ax2 * S_LEN * HD + (size_t)s * HD + d2];
  float s2 = sb[(size_t)ax2 * S_LEN * HD + (size_t)s * HD + d2];
  float x1 = row[d1], x2 = row[d2];
  float y1 = x1 * c1 - x2 * s1;
  float y2 = x2 * c2 + x1 * s2;
  _Float16* dp;
  size_t base;
  if (hh < NHEADS) { dp = q16; base = (size_t)s * HID + hh * HD; }
  else { dp = k16; base = (size_t)s * 512 + (hh - NHEADS) * HD; }
  dp[base + d1] = (_Float16)y1;
  dp[base + d2] = (_Float16)y2;
}

// ---------------- V transpose from fp32 qkv: vt[j][d][k] (bf16) ----------------
__global__ void vtrans(const float* __restrict__ qf, __hip_bfloat16* __restrict__ vt) {
  __shared__ __hip_bfloat16 t[64][65];
  const int j = blockIdx.z;
  const int d0 = blockIdx.y * 64;
  const int k0 = blockIdx.x * 64;
  const int tid = threadIdx.x;
#pragma unroll
  for (int half = 0; half < 2; ++half) {
    int r = half * 32 + (tid >> 3);
    int c = (tid & 7) * 8;
    const float* p = qf + (size_t)(k0 + r) * QKV_N + (HID + 512) + j * HD + d0 + c;
    float4 a = ((const float4*)p)[0];
    float4 b = ((const float4*)p)[1];
    t[c + 0][r] = __float2bfloat16(a.x); t[c + 1][r] = __float2bfloat16(a.y);
    t[c + 2][r] = __float2bfloat16(a.z); t[c + 3][r] = __float2bfloat16(a.w);
    t[c + 4][r] = __float2bfloat16(b.x); t[c + 5][r] = __float2bfloat16(b.y);
    t[c + 6][r] = __float2bfloat16(b.z); t[c + 7][r] = __float2bfloat16(b.w);
  }
  __syncthreads();
#pragma unroll
  for (int half = 0; half < 2; ++half) {
    int r = half * 32 + (tid >> 3);
    int c = (tid & 7) * 8;
    __hip_bfloat16 tmp[8];
#pragma unroll
    for (int u = 0; u < 8; ++u) tmp[u] = t[r][c + u];
    *(bf16x8*)&vt[(size_t)j * (HD * S_LEN) + (size_t)(d0 + r) * S_LEN + k0 + c] = *(const bf16x8*)tmp;
  }
}

// ------------- swizzled staging: LDS linear dest, pre-swizzled global src -------------
// 64 rows x 128 cols of 2-byte elems (16 slots/row of 8): slot ^= row&7
template <typename T>
__device__ __forceinline__ void stageK_sw(T* dst, const T* gsrc, int ldg, int tid) {
#pragma unroll
  for (int it = 0; it < 4; ++it) {
    int c = it * 256 + tid;
    int rw = c >> 4, sl = c & 15;
    int gcol = (sl ^ (rw & 7)) << 3;
    gl_lds16(gsrc + (size_t)rw * ldg + gcol, dst + (size_t)(it * 256 + (tid & 192)) * 8);
  }
}
// 128 rows x 64 cols (8 slots/row): slot ^= row&7
__device__ __forceinline__ void stageV_sw(__hip_bfloat16* dst, const __hip_bfloat16* gsrc,
                                          int ldg, int tid) {
#pragma unroll
  for (int it = 0; it < 4; ++it) {
    int c = it * 256 + tid;
    int rw = c >> 3, sl = c & 7;
    int gcol = (sl ^ (rw & 7)) << 3;
    gl_lds16(gsrc + (size_t)rw * ldg + gcol, dst + (size_t)(it * 256 + (tid & 192)) * 8);
  }
}

// ---------------- fused l+scores: dynamic jobs, 2-phase K prefetch ----------------
__global__ __launch_bounds__(256, 2) void attn_ls(
    const _Float16* __restrict__ q16, const _Float16* __restrict__ k16,
    float* __restrict__ scores, int* __restrict__ ctr) {
  __shared__ _Float16 Kh[2][64 * 128];  // 32 KB
  __shared__ int sj;
  const int tid = threadIdx.x;
  const int lane = tid & 63, w = tid >> 6;
  const int l15 = lane & 15, l4 = lane >> 4;
  const int sw = l15 & 7;
  for (;;) {
    __syncthreads();
    if (tid == 0) sj = atomicAdd(ctr, 1);
    __syncthreads();
    const int j = sj;
    if (j >= NJOBS) return;
    const int qb = 31 - j / 28, h = j % 28;
    const int hkv = h / NREP;
    const int nt = qb + 1;
    f16x8 qh[4];
    {
      const _Float16* qp = q16 + (size_t)(qb * 64 + w * 16 + l15) * HID + h * HD + l4 * 8;
#pragma unroll
      for (int kk = 0; kk < 4; ++kk) qh[kk] = *(const f16x8*)(qp + kk * 32);
    }
    // ---- sweep 1: l ----
    float lsum[4] = {0.f, 0.f, 0.f, 0.f};
    stageK_sw(Kh[0], k16 + hkv * HD, 512, tid);
    __syncthreads();
    for (int kt = 0; kt < nt; ++kt) {
      if (kt + 1 < nt)
        stageK_sw(Kh[(kt + 1) & 1], k16 + (size_t)((kt + 1) * 64) * 512 + hkv * HD, 512, tid);
      const _Float16* Kc = Kh[kt & 1];
      f32x4 acc[4] = {};
#pragma unroll
      for (int kk = 0; kk < 4; ++kk)
#pragma unroll
        for (int n = 0; n < 4; ++n) {
          f16x8 bh = *(const f16x8*)&Kc[(n * 16 + l15) * 128 + (((kk * 4 + l4) ^ sw) << 3)];
          acc[n] = MFMA_F16(qh[kk], bh, acc[n]);
        }
      const bool diag = (kt == qb);
#pragma unroll
      for (int r = 0; r < 4; ++r) {
        int rowg = qb * 64 + w * 16 + l4 * 4 + r;
#pragma unroll
        for (int n = 0; n < 4; ++n)
          if (!(diag && (kt * 64 + n * 16 + l15) > rowg))
            lsum[r] += __expf(acc[n][r] * SCALE);
      }
      __syncthreads();
    }
    float invl[4];
#pragma unroll
    for (int r = 0; r < 4; ++r) {
      float s = lsum[r];
      s += __shfl_xor(s, 1);
      s += __shfl_xor(s, 2);
      s += __shfl_xor(s, 4);
      s += __shfl_xor(s, 8);
      invl[r] = 1.0f / s;
    }
    // ---- sweep 2: scores ----
    stageK_sw(Kh[0], k16 + hkv * HD, 512, tid);
    __syncthreads();
    for (int kt = 0; kt < nt; ++kt) {
      if (kt + 1 < nt)
        stageK_sw(Kh[(kt + 1) & 1], k16 + (size_t)((kt + 1) * 64) * 512 + hkv * HD, 512, tid);
      const _Float16* Kc = Kh[kt & 1];
      f32x4 acc[4] = {};
#pragma unroll
      for (int kk = 0; kk < 4; ++kk)
#pragma unroll
        for (int n = 0; n < 4; ++n) {
          f16x8 bh = *(const f16x8*)&Kc[(n * 16 + l15) * 128 + (((kk * 4 + l4) ^ sw) << 3)];
          acc[n] = MFMA_F16(qh[kk], bh, acc[n]);
        }
      const bool diag = (kt == qb);
      float colsum[4] = {0.f, 0.f, 0.f, 0.f};
#pragma unroll
      for (int r = 0; r < 4; ++r) {
        int rowg = qb * 64 + w * 16 + l4 * 4 + r;
#pragma unroll
        for (int n = 0; n < 4; ++n)
          if (!(diag && (kt * 64 + n * 16 + l15) > rowg))
            colsum[n] += __expf(acc[n][r] * SCALE) * invl[r];
      }
#pragma unroll
      for (int n = 0; n < 4; ++n) {
        colsum[n] += __shfl_xor(colsum[n], 16);
        colsum[n] += __shfl_xor(colsum[n], 32);
      }
      if (lane < 16) {
#pragma unroll
        for (int n = 0; n < 4; ++n)
          atomicAdd(&scores[h * S_LEN + kt * 64 + n * 16 + lane], colsum[n]);
      }
      __syncthreads();
    }
  }
}

// ---------------- exact top-k (boundary search) -> keep mask ----------------
__global__ void h2o_topk(const float* __restrict__ scores, unsigned char* __restrict__ keep) {
  const int h = blockIdx.x;
  const int tid = threadIdx.x;
  const int MS = 409, ME = 1844, REGN = 1435, KSEL = 204;
  __shared__ float sv[1435];
  __shared__ int cnt, eqn;
  __shared__ int eqlist[256];
  for (int i = tid; i < REGN; i += 256) sv[i] = scores[h * S_LEN + MS + i];
  for (int i = tid; i < S_LEN; i += 256)
    keep[h * S_LEN + i] = (i < MS || i >= ME) ? 1 : 0;
  __syncthreads();
  unsigned lo = 0u, hi = 0x7f800000u;
  while (hi - lo > 1u) {
    unsigned mid = lo + ((hi - lo) >> 1);
    if (tid == 0) cnt = 0;
    __syncthreads();
    int lc = 0;
    for (int i = tid; i < REGN; i += 256) lc += (__float_as_uint(sv[i]) >= mid) ? 1 : 0;
    if (lc) atomicAdd(&cnt, lc);
    __syncthreads();
    int c = cnt;
    __syncthreads();
    if (c >= KSEL) lo = mid;
    else hi = mid;
  }
  if (tid == 0) { cnt = 0; eqn = 0; }
  __syncthreads();
  int lgt = 0;
  for (int i = tid; i < REGN; i += 256) {
    unsigned b = __float_as_uint(sv[i]);
    if (b > lo) { keep[h * S_LEN + MS + i] = 1; lgt++; }
    else if (b == lo) {
      int p = atomicAdd(&eqn, 1);
      if (p < 256) eqlist[p] = i;
    }
  }
  if (lgt) atomicAdd(&cnt, lgt);
  __syncthreads();
  if (tid == 0) {
    int r = KSEL - cnt;
    int ne = eqn > 256 ? 256 : eqn;
    for (int t = 0; t < r; ++t) {
      int best = 0x7fffffff, bj = -1;
      for (int j = 0; j < ne; ++j)
        if (eqlist[j] < best) { best = eqlist[j]; bj = j; }
      if (bj < 0) break;
      keep[h * S_LEN + MS + best] = 1;
      eqlist[bj] = 0x7fffffff;
    }
  }
}

// ---------------- pruned+renormalized output: dynamic jobs, 2-phase K/V prefetch ----------------
__global__ __launch_bounds__(256, 2) void attn_out(
    const _Float16* __restrict__ q16, const _Float16* __restrict__ k16,
    const __hip_bfloat16* __restrict__ vt, const unsigned char* __restrict__ keep,
    _Float16* __restrict__ ctx, int* __restrict__ ctr) {
  __shared__ _Float16 Kh[2][64 * 128];        // 32 KB
  __shared__ __hip_bfloat16 Vtl[2][128 * 64]; // 32 KB
  __shared__ __hip_bfloat16 Wt[4][16 * 64];   // 8 KB -> 72 KB total (2 blocks/CU)
  __shared__ int sj;
  const int tid = threadIdx.x;
  const int lane = tid & 63, w = tid >> 6;
  const int l15 = lane & 15, l4 = lane >> 4;
  const int sw = l15 & 7;
  for (;;) {
    __syncthreads();
    if (tid == 0) sj = atomicAdd(ctr, 1);
    __syncthreads();
    const int j = sj;
    if (j >= NJOBS) return;
    const int qb = 31 - j / 28, h = j % 28;
    const int hkv = h / NREP;
    const int nt = qb + 1;
    f16x8 qh[4];
    {
      const _Float16* qp = q16 + (size_t)(qb * 64 + w * 16 + l15) * HID + h * HD + l4 * 8;
#pragma unroll
      for (int kk = 0; kk < 4; ++kk) qh[kk] = *(const f16x8*)(qp + kk * 32);
    }
    f32x4 o[8] = {};
    float dens[4] = {0.f, 0.f, 0.f, 0.f};
    stageK_sw(Kh[0], k16 + hkv * HD, 512, tid);
    stageV_sw(Vtl[0], vt + (size_t)hkv * (HD * S_LEN), S_LEN, tid);
    __syncthreads();
    for (int kt = 0; kt < nt; ++kt) {
      if (kt + 1 < nt) {
        stageK_sw(Kh[(kt + 1) & 1], k16 + (size_t)((kt + 1) * 64) * 512 + hkv * HD, 512, tid);
        stageV_sw(Vtl[(kt + 1) & 1], vt + (size_t)hkv * (HD * S_LEN) + (kt + 1) * 64, S_LEN, tid);
      }
      const _Float16* Kc = Kh[kt & 1];
      const __hip_bfloat16* Vc = Vtl[kt & 1];
      f32x4 acc[4] = {};
#pragma unroll
      for (int kk = 0; kk < 4; ++kk)
#pragma unroll
        for (int n = 0; n < 4; ++n) {
          f16x8 bh = *(const f16x8*)&Kc[(n * 16 + l15) * 128 + (((kk * 4 + l4) ^ sw) << 3)];
          acc[n] = MFMA_F16(qh[kk], bh, acc[n]);
        }
      const bool diag = (kt == qb);
      float kf[4];
#pragma unroll
      for (int n = 0; n < 4; ++n)
        kf[n] = (float)keep[h * S_LEN + kt * 64 + n * 16 + l15];
#pragma unroll
      for (int r = 0; r < 4; ++r) {
        int rowg = qb * 64 + w * 16 + l4 * 4 + r;
        int row16 = l4 * 4 + r;
#pragma unroll
        for (int n = 0; n < 4; ++n) {
          int coll = n * 16 + l15;
          float wv = 0.f;
          if (!diag || (kt * 64 + coll) <= rowg)
            wv = kf[n] * __expf(acc[n][r] * SCALE);
          dens[r] += wv;
          Wt[w][row16 * 64 + (coll ^ ((row16 & 7) << 3))] = __float2bfloat16(wv);
        }
      }
      // PV: o[n] += W(16x64) * Vt(row=d)
#pragma unroll
      for (int kk = 0; kk < 2; ++kk) {
        bf16x8 af = *(const bf16x8*)&Wt[w][l15 * 64 + ((kk * 32 + l4 * 8) ^ (sw << 3))];
#pragma unroll
        for (int n = 0; n < 8; ++n) {
          bf16x8 bf = *(const bf16x8*)&Vc[(n * 16 + l15) * 64 + (((kk * 4 + l4) ^ sw) << 3)];
          o[n] = MFMA_B16(af, bf, o[n]);
        }
      }
      __syncthreads();
    }
    float invd[4];
#pragma unroll
    for (int r = 0; r < 4; ++r) {
      float d = dens[r];
      d += __shfl_xor(d, 1);
      d += __shfl_xor(d, 2);
      d += __shfl_xor(d, 4);
      d += __shfl_xor(d, 8);
      invd[r] = 1.0f / fmaxf(d, 1e-30f);
    }
#pragma unroll
    for (int n = 0; n < 8; ++n)
#pragma unroll
      for (int r = 0; r < 4; ++r) {
        size_t row = qb * 64 + w * 16 + l4 * 4 + r;
        size_t col = h * HD + n * 16 + l15;
        ctx[row * HID + col] = (_Float16)(o[n][r] * invd[r]);
      }
    // zero accumulators happen naturally at next job (re-declared per iteration)
  }
}

// ---------------- host glue ----------------
extern "C" void kernel_launch(void* const* d_in, const int* in_sizes, int n_in,
                              void* d_out, int out_size, void* d_ws, size_t ws_size,
                              hipStream_t stream) {
  const float* hidden = (const float*)d_in[0];
  const float* cosb = (const float*)d_in[2];
  const float* sinb = (const float*)d_in[3];
  const float* q_w = (const float*)d_in[4];
  const float* q_b = (const float*)d_in[5];
  const float* k_w = (const float*)d_in[6];
  const float* k_b = (const float*)d_in[7];
  const float* v_w = (const float*)d_in[8];
  const float* v_b = (const float*)d_in[9];
  const float* o_w = (const float*)d_in[10];

  char* ws = (char*)d_ws;
  // Phase A (QKV GEMM):
  float* qkv_f32 = (float*)(ws + 0);                        // 37,748,736
  _Float16* hf16 = (_Float16*)(ws + 37748736);              // 14,680,064 -> 52,428,800
  _Float16* wqkv16 = (_Float16*)(ws + 52428800);            // 33,030,144 -> 85,458,944
  float* biasb = (float*)(ws + 85458944);                   //     18,432 -> 85,477,376
  // Phase B overlays:
  _Float16* q16 = (_Float16*)(ws + 37748736);               // 14,680,064 (over dead hf16)
  _Float16* wo16 = (_Float16*)(ws + 52428800);              // 25,690,112 (over dead wqkv16)
  _Float16* k16 = (_Float16*)(ws + 85477376);               //  2,097,152 -> 87,574,528
  __hip_bfloat16* vt = (__hip_bfloat16*)(ws + 87574528);    //  2,097,152 -> 89,671,680
  float* scores = (float*)(ws + 89671680);                  //    229,376 -> 89,901,056
  unsigned char* keep = (unsigned char*)(ws + 89901056);    //     57,344 -> 89,958,400
  int* ctrs = (int*)(ws + 89958400);                        //          8 -> 89,958,408 peak
  // Phase C overlay (qkv_f32 dead after rope+vtrans):
  _Float16* ctx16 = (_Float16*)(ws + 0);                    // 14,680,064

  hipMemcpyAsync(biasb, q_b, 3584 * 4, hipMemcpyDeviceToDevice, stream);
  hipMemcpyAsync(biasb + 3584, k_b, 512 * 4, hipMemcpyDeviceToDevice, stream);
  hipMemcpyAsync(biasb + 4096, v_b, 512 * 4, hipMemcpyDeviceToDevice, stream);

  // fp16 operand conversion
  cvt_f32_f16<<<7168, 256, 0, stream>>>(hidden, hf16, 1835008);
  cvt_f32_f16<<<12544, 256, 0, stream>>>(q_w, wqkv16, 3211264);
  cvt_f32_f16<<<1792, 256, 0, stream>>>(k_w, wqkv16 + (size_t)3584 * 3584, 458752);
  cvt_f32_f16<<<1792, 256, 0, stream>>>(v_w, wqkv16 + (size_t)4096 * 3584, 458752);

  // QKV projection (fp16 MFMA, fp32 accum, +bias)
  gemm_f16<true><<<dim3(36, 16), 256, 0, stream>>>(hf16, HID, wqkv16, HID,
                                                   biasb, qkv_f32, QKV_N, HID);

  // o_w conversion into now-dead wqkv space (stream-ordered)
  cvt_f32_f16<<<12544, 256, 0, stream>>>(o_w, wo16, 3211264);

  rope_f16<<<16384, 256, 0, stream>>>(qkv_f32, cosb, sinb, q16, k16);
  vtrans<<<dim3(32, 2, 4), 256, 0, stream>>>(qkv_f32, vt);
  hipMemsetAsync(scores, 0, NHEADS * S_LEN * 4, stream);
  hipMemsetAsync(ctrs, 0, 8, stream);

  attn_ls<<<512, 256, 0, stream>>>(q16, k16, scores, &ctrs[0]);
  h2o_topk<<<28, 256, 0, stream>>>(scores, keep);
  attn_out<<<512, 256, 0, stream>>>(q16, k16, vt, keep, ctx16, &ctrs[1]);

  // output projection (fp16 MFMA, fp32 accum)
  gemm_f16<false><<<dim3(28, 16), 256, 0, stream>>>(ctx16, HID, wo16, HID,
                                                    nullptr, (float*)d_out, HID, HID);
}

// Round 10
// 436.450 us; speedup vs baseline: 3.9408x; 1.0513x over previous
//
#include <hip/hip_runtime.h>
#include <hip/hip_bf16.h>
#include <stdint.h>

#define S_LEN 2048
#define HID 3584
#define NHEADS 28
#define KVHEADS 4
#define HD 128
#define QKV_N 4608
#define NREP 7
#define SCALE 0.08838834764831845f
#define NJOBS 896

typedef __attribute__((ext_vector_type(8))) short bf16x8;
typedef __attribute__((ext_vector_type(8))) _Float16 f16x8;
typedef __attribute__((ext_vector_type(4))) float f32x4;

#define MFMA_B16(a, b, c) __builtin_amdgcn_mfma_f32_16x16x32_bf16((a), (b), (c), 0, 0, 0)
#define MFMA_F16(a, b, c) __builtin_amdgcn_mfma_f32_16x16x32_f16((a), (b), (c), 0, 0, 0)

__device__ __forceinline__ void gl_lds16(const void* g, void* l) {
  __builtin_amdgcn_global_load_lds(
      (__attribute__((address_space(1))) void*)(void*)(g),
      (__attribute__((address_space(3))) void*)(l), 16, 0, 0);
}

// ---------------- fp32 -> fp16 conversion ----------------
__global__ void cvt_f32_f16(const float* __restrict__ src, _Float16* __restrict__ dst, int n4) {
  int i = blockIdx.x * 256 + threadIdx.x;
  if (i >= n4) return;
  float4 v = ((const float4*)src)[i];
  _Float16 t[4] = {(_Float16)v.x, (_Float16)v.y, (_Float16)v.z, (_Float16)v.w};
  ((uint2*)dst)[i] = *(const uint2*)t;
}

// ---------------- fp16 GEMM: C = A * B^T (+bias) ----------------
// BK=64, XOR-swizzled LDS (slot^row&7, pre-swizzled global src), 4 blocks/CU.
template <bool HAS_BIAS>
__global__ __launch_bounds__(256, 4) void gemm_f16(
    const _Float16* __restrict__ A, int lda,
    const _Float16* __restrict__ B, int ldb,
    const float* __restrict__ bias, float* __restrict__ C, int ldc, int K) {
  __shared__ _Float16 lA[128 * 64], lB[128 * 64];  // 32 KB total
  const int tid = threadIdx.x;
  const int lane = tid & 63;
  const int wid = tid >> 6;
  const int wr = wid >> 1, wc = wid & 1;
  const int l15 = lane & 15, l4 = lane >> 4;
  const int bm = blockIdx.y * 128, bn = blockIdx.x * 128;
  f32x4 acc[4][4] = {};
  for (int k0 = 0; k0 < K; k0 += 64) {
    __syncthreads();
#pragma unroll
    for (int it = 0; it < 4; ++it) {
      int c = it * 256 + tid;
      int rw = c >> 3, sl = c & 7;
      int gcol = (sl ^ (rw & 7)) << 3;
      int lo = (it * 256 + (tid & 192)) * 8;
      gl_lds16(A + (size_t)(bm + rw) * lda + (k0 + gcol), &lA[lo]);
      gl_lds16(B + (size_t)(bn + rw) * ldb + (k0 + gcol), &lB[lo]);
    }
    __syncthreads();
#pragma unroll
    for (int kk = 0; kk < 2; ++kk) {
      f16x8 af[4], bf[4];
#pragma unroll
      for (int m = 0; m < 4; ++m) {
        int rA = wr * 64 + m * 16 + l15;
        af[m] = *(const f16x8*)&lA[rA * 64 + (((kk * 4 + l4) ^ (rA & 7)) << 3)];
      }
#pragma unroll
      for (int n = 0; n < 4; ++n) {
        int rB = wc * 64 + n * 16 + l15;
        bf[n] = *(const f16x8*)&lB[rB * 64 + (((kk * 4 + l4) ^ (rB & 7)) << 3)];
      }
#pragma unroll
      for (int m = 0; m < 4; ++m)
#pragma unroll
        for (int n = 0; n < 4; ++n)
          acc[m][n] = MFMA_F16(af[m], bf[n], acc[m][n]);
    }
  }
#pragma unroll
  for (int m = 0; m < 4; ++m)
#pragma unroll
    for (int n = 0; n < 4; ++n)
#pragma unroll
      for (int r = 0; r < 4; ++r) {
        size_t row = bm + wr * 64 + m * 16 + l4 * 4 + r;
        size_t col = bn + wc * 64 + n * 16 + l15;
        float v = acc[m][n][r];
        if (HAS_BIAS) v += bias[col];
        C[row * ldc + col] = v;
      }
}

// ---------------- rope on fp32 qkv, emit fp16 Q/K ----------------
__global__ void rope_f16(const float* __restrict__ qf, const float* __restrict__ cb,
                         const float* __restrict__ sb,
                         _Float16* __restrict__ q16, _Float16* __restrict__ k16) {
  int idx = blockIdx.x * 256 + threadIdx.x;  // 2048 * 32 * 64
  int d1 = idx & 63;
  int hh = (idx >> 6) & 31;
  int s = idx >> 11;
  if (s >= S_LEN) return;
  const float* row = qf + (size_t)s * QKV_N + (hh < NHEADS ? hh * HD : HID + (hh - NHEADS) * HD);
  int d2 = d1 + 64;
  int ax1 = (d1 < 32) ? 0 : 1;  // sections: [0,32)->ax0, [32,80)->ax1, [80,128)->ax2
  int ax2 = (d2 < 80) ? 1 : 2;
  float c1 = cb[(size_t)ax1 * S_LEN * HD + (size_t)s * HD + d1];
  float s1 = sb[(size_t)ax1 * S_LEN * HD + (size_t)s * HD + d1];
  float c2 = cb[(size_t)ax2 * S_LEN * HD + (size_t)s * HD + d2];
  float s2 = sb[(size_t)ax2 * S_LEN * HD + (size_t)s * HD + d2];
  float x1 = row[d1], x2 = row[d2];
  float y1 = x1 * c1 - x2 * s1;
  float y2 = x2 * c2 + x1 * s2;
  _Float16* dp;
  size_t base;
  if (hh < NHEADS) { dp = q16; base = (size_t)s * HID + hh * HD; }
  else { dp = k16; base = (size_t)s * 512 + (hh - NHEADS) * HD; }
  dp[base + d1] = (_Float16)y1;
  dp[base + d2] = (_Float16)y2;
}

// ---------------- V transpose from fp32 qkv: vt[j][d][k] (bf16) ----------------
__global__ void vtrans(const float* __restrict__ qf, __hip_bfloat16* __restrict__ vt) {
  __shared__ __hip_bfloat16 t[64][65];
  const int j = blockIdx.z;
  const int d0 = blockIdx.y * 64;
  const int k0 = blockIdx.x * 64;
  const int tid = threadIdx.x;
#pragma unroll
  for (int half = 0; half < 2; ++half) {
    int r = half * 32 + (tid >> 3);
    int c = (tid & 7) * 8;
    const float* p = qf + (size_t)(k0 + r) * QKV_N + (HID + 512) + j * HD + d0 + c;
    float4 a = ((const float4*)p)[0];
    float4 b = ((const float4*)p)[1];
    t[c + 0][r] = __float2bfloat16(a.x); t[c + 1][r] = __float2bfloat16(a.y);
    t[c + 2][r] = __float2bfloat16(a.z); t[c + 3][r] = __float2bfloat16(a.w);
    t[c + 4][r] = __float2bfloat16(b.x); t[c + 5][r] = __float2bfloat16(b.y);
    t[c + 6][r] = __float2bfloat16(b.z); t[c + 7][r] = __float2bfloat16(b.w);
  }
  __syncthreads();
#pragma unroll
  for (int half = 0; half < 2; ++half) {
    int r = half * 32 + (tid >> 3);
    int c = (tid & 7) * 8;
    __hip_bfloat16 tmp[8];
#pragma unroll
    for (int u = 0; u < 8; ++u) tmp[u] = t[r][c + u];
    *(bf16x8*)&vt[(size_t)j * (HD * S_LEN) + (size_t)(d0 + r) * S_LEN + k0 + c] = *(const bf16x8*)tmp;
  }
}

// ------------- swizzled staging: LDS linear dest, pre-swizzled global src -------------
// 64 rows x 128 cols of 2-byte elems (16 slots/row of 8): slot ^= row&7
template <typename T>
__device__ __forceinline__ void stageK_sw(T* dst, const T* gsrc, int ldg, int tid) {
#pragma unroll
  for (int it = 0; it < 4; ++it) {
    int c = it * 256 + tid;
    int rw = c >> 4, sl = c & 15;
    int gcol = (sl ^ (rw & 7)) << 3;
    gl_lds16(gsrc + (size_t)rw * ldg + gcol, dst + (size_t)(it * 256 + (tid & 192)) * 8);
  }
}
// 128 rows x 64 cols (8 slots/row): slot ^= row&7
__device__ __forceinline__ void stageV_sw(__hip_bfloat16* dst, const __hip_bfloat16* gsrc,
                                          int ldg, int tid) {
#pragma unroll
  for (int it = 0; it < 4; ++it) {
    int c = it * 256 + tid;
    int rw = c >> 3, sl = c & 7;
    int gcol = (sl ^ (rw & 7)) << 3;
    gl_lds16(gsrc + (size_t)rw * ldg + gcol, dst + (size_t)(it * 256 + (tid & 192)) * 8);
  }
}

// ---------------- fused l+scores: dynamic jobs, 2-phase K prefetch ----------------
__global__ __launch_bounds__(256, 2) void attn_ls(
    const _Float16* __restrict__ q16, const _Float16* __restrict__ k16,
    float* __restrict__ scores, int* __restrict__ ctr) {
  __shared__ _Float16 Kh[2][64 * 128];  // 32 KB
  __shared__ int sj;
  const int tid = threadIdx.x;
  const int lane = tid & 63, w = tid >> 6;
  const int l15 = lane & 15, l4 = lane >> 4;
  const int sw = l15 & 7;
  for (;;) {
    __syncthreads();
    if (tid == 0) sj = atomicAdd(ctr, 1);
    __syncthreads();
    const int j = sj;
    if (j >= NJOBS) return;
    const int qb = 31 - j / 28, h = j % 28;
    const int hkv = h / NREP;
    const int nt = qb + 1;
    f16x8 qh[4];
    {
      const _Float16* qp = q16 + (size_t)(qb * 64 + w * 16 + l15) * HID + h * HD + l4 * 8;
#pragma unroll
      for (int kk = 0; kk < 4; ++kk) qh[kk] = *(const f16x8*)(qp + kk * 32);
    }
    // ---- sweep 1: l ----
    float lsum[4] = {0.f, 0.f, 0.f, 0.f};
    stageK_sw(Kh[0], k16 + hkv * HD, 512, tid);
    __syncthreads();
    for (int kt = 0; kt < nt; ++kt) {
      if (kt + 1 < nt)
        stageK_sw(Kh[(kt + 1) & 1], k16 + (size_t)((kt + 1) * 64) * 512 + hkv * HD, 512, tid);
      const _Float16* Kc = Kh[kt & 1];
      f32x4 acc[4] = {};
#pragma unroll
      for (int kk = 0; kk < 4; ++kk)
#pragma unroll
        for (int n = 0; n < 4; ++n) {
          f16x8 bh = *(const f16x8*)&Kc[(n * 16 + l15) * 128 + (((kk * 4 + l4) ^ sw) << 3)];
          acc[n] = MFMA_F16(qh[kk], bh, acc[n]);
        }
      const bool diag = (kt == qb);
#pragma unroll
      for (int r = 0; r < 4; ++r) {
        int rowg = qb * 64 + w * 16 + l4 * 4 + r;
#pragma unroll
        for (int n = 0; n < 4; ++n)
          if (!(diag && (kt * 64 + n * 16 + l15) > rowg))
            lsum[r] += __expf(acc[n][r] * SCALE);
      }
      __syncthreads();
    }
    float invl[4];
#pragma unroll
    for (int r = 0; r < 4; ++r) {
      float s = lsum[r];
      s += __shfl_xor(s, 1);
      s += __shfl_xor(s, 2);
      s += __shfl_xor(s, 4);
      s += __shfl_xor(s, 8);
      invl[r] = 1.0f / s;
    }
    // ---- sweep 2: scores ----
    stageK_sw(Kh[0], k16 + hkv * HD, 512, tid);
    __syncthreads();
    for (int kt = 0; kt < nt; ++kt) {
      if (kt + 1 < nt)
        stageK_sw(Kh[(kt + 1) & 1], k16 + (size_t)((kt + 1) * 64) * 512 + hkv * HD, 512, tid);
      const _Float16* Kc = Kh[kt & 1];
      f32x4 acc[4] = {};
#pragma unroll
      for (int kk = 0; kk < 4; ++kk)
#pragma unroll
        for (int n = 0; n < 4; ++n) {
          f16x8 bh = *(const f16x8*)&Kc[(n * 16 + l15) * 128 + (((kk * 4 + l4) ^ sw) << 3)];
          acc[n] = MFMA_F16(qh[kk], bh, acc[n]);
        }
      const bool diag = (kt == qb);
      float colsum[4] = {0.f, 0.f, 0.f, 0.f};
#pragma unroll
      for (int r = 0; r < 4; ++r) {
        int rowg = qb * 64 + w * 16 + l4 * 4 + r;
#pragma unroll
        for (int n = 0; n < 4; ++n)
          if (!(diag && (kt * 64 + n * 16 + l15) > rowg))
            colsum[n] += __expf(acc[n][r] * SCALE) * invl[r];
      }
#pragma unroll
      for (int n = 0; n < 4; ++n) {
        colsum[n] += __shfl_xor(colsum[n], 16);
        colsum[n] += __shfl_xor(colsum[n], 32);
      }
      if (lane < 16) {
#pragma unroll
        for (int n = 0; n < 4; ++n)
          atomicAdd(&scores[h * S_LEN + kt * 64 + n * 16 + lane], colsum[n]);
      }
      __syncthreads();
    }
  }
}

// ---------------- exact top-k (boundary search) -> keep mask ----------------
__global__ void h2o_topk(const float* __restrict__ scores, unsigned char* __restrict__ keep) {
  const int h = blockIdx.x;
  const int tid = threadIdx.x;
  const int MS = 409, ME = 1844, REGN = 1435, KSEL = 204;
  __shared__ float sv[1435];
  __shared__ int cnt, eqn;
  __shared__ int eqlist[256];
  for (int i = tid; i < REGN; i += 256) sv[i] = scores[h * S_LEN + MS + i];
  for (int i = tid; i < S_LEN; i += 256)
    keep[h * S_LEN + i] = (i < MS || i >= ME) ? 1 : 0;
  __syncthreads();
  unsigned lo = 0u, hi = 0x7f800000u;
  while (hi - lo > 1u) {
    unsigned mid = lo + ((hi - lo) >> 1);
    if (tid == 0) cnt = 0;
    __syncthreads();
    int lc = 0;
    for (int i = tid; i < REGN; i += 256) lc += (__float_as_uint(sv[i]) >= mid) ? 1 : 0;
    if (lc) atomicAdd(&cnt, lc);
    __syncthreads();
    int c = cnt;
    __syncthreads();
    if (c >= KSEL) lo = mid;
    else hi = mid;
  }
  if (tid == 0) { cnt = 0; eqn = 0; }
  __syncthreads();
  int lgt = 0;
  for (int i = tid; i < REGN; i += 256) {
    unsigned b = __float_as_uint(sv[i]);
    if (b > lo) { keep[h * S_LEN + MS + i] = 1; lgt++; }
    else if (b == lo) {
      int p = atomicAdd(&eqn, 1);
      if (p < 256) eqlist[p] = i;
    }
  }
  if (lgt) atomicAdd(&cnt, lgt);
  __syncthreads();
  if (tid == 0) {
    int r = KSEL - cnt;
    int ne = eqn > 256 ? 256 : eqn;
    for (int t = 0; t < r; ++t) {
      int best = 0x7fffffff, bj = -1;
      for (int j = 0; j < ne; ++j)
        if (eqlist[j] < best) { best = eqlist[j]; bj = j; }
      if (bj < 0) break;
      keep[h * S_LEN + MS + best] = 1;
      eqlist[bj] = 0x7fffffff;
    }
  }
}

// ---------------- pruned+renormalized output: dynamic jobs, 2-phase K/V prefetch ----------------
__global__ __launch_bounds__(256, 2) void attn_out(
    const _Float16* __restrict__ q16, const _Float16* __restrict__ k16,
    const __hip_bfloat16* __restrict__ vt, const unsigned char* __restrict__ keep,
    _Float16* __restrict__ ctx, int* __restrict__ ctr) {
  __shared__ _Float16 Kh[2][64 * 128];        // 32 KB
  __shared__ __hip_bfloat16 Vtl[2][128 * 64]; // 32 KB
  __shared__ __hip_bfloat16 Wt[4][16 * 64];   // 8 KB -> 72 KB total (2 blocks/CU)
  __shared__ int sj;
  const int tid = threadIdx.x;
  const int lane = tid & 63, w = tid >> 6;
  const int l15 = lane & 15, l4 = lane >> 4;
  const int sw = l15 & 7;
  for (;;) {
    __syncthreads();
    if (tid == 0) sj = atomicAdd(ctr, 1);
    __syncthreads();
    const int j = sj;
    if (j >= NJOBS) return;
    const int qb = 31 - j / 28, h = j % 28;
    const int hkv = h / NREP;
    const int nt = qb + 1;
    f16x8 qh[4];
    {
      const _Float16* qp = q16 + (size_t)(qb * 64 + w * 16 + l15) * HID + h * HD + l4 * 8;
#pragma unroll
      for (int kk = 0; kk < 4; ++kk) qh[kk] = *(const f16x8*)(qp + kk * 32);
    }
    f32x4 o[8] = {};
    float dens[4] = {0.f, 0.f, 0.f, 0.f};
    stageK_sw(Kh[0], k16 + hkv * HD, 512, tid);
    stageV_sw(Vtl[0], vt + (size_t)hkv * (HD * S_LEN), S_LEN, tid);
    __syncthreads();
    for (int kt = 0; kt < nt; ++kt) {
      if (kt + 1 < nt) {
        stageK_sw(Kh[(kt + 1) & 1], k16 + (size_t)((kt + 1) * 64) * 512 + hkv * HD, 512, tid);
        stageV_sw(Vtl[(kt + 1) & 1], vt + (size_t)hkv * (HD * S_LEN) + (kt + 1) * 64, S_LEN, tid);
      }
      const _Float16* Kc = Kh[kt & 1];
      const __hip_bfloat16* Vc = Vtl[kt & 1];
      f32x4 acc[4] = {};
#pragma unroll
      for (int kk = 0; kk < 4; ++kk)
#pragma unroll
        for (int n = 0; n < 4; ++n) {
          f16x8 bh = *(const f16x8*)&Kc[(n * 16 + l15) * 128 + (((kk * 4 + l4) ^ sw) << 3)];
          acc[n] = MFMA_F16(qh[kk], bh, acc[n]);
        }
      const bool diag = (kt == qb);
      float kf[4];
#pragma unroll
      for (int n = 0; n < 4; ++n)
        kf[n] = (float)keep[h * S_LEN + kt * 64 + n * 16 + l15];
#pragma unroll
      for (int r = 0; r < 4; ++r) {
        int rowg = qb * 64 + w * 16 + l4 * 4 + r;
        int row16 = l4 * 4 + r;
#pragma unroll
        for (int n = 0; n < 4; ++n) {
          int coll = n * 16 + l15;
          float wv = 0.f;
          if (!diag || (kt * 64 + coll) <= rowg)
            wv = kf[n] * __expf(acc[n][r] * SCALE);
          dens[r] += wv;
          Wt[w][row16 * 64 + (coll ^ ((row16 & 7) << 3))] = __float2bfloat16(wv);
        }
      }
      // PV: o[n] += W(16x64) * Vt(row=d)
#pragma unroll
      for (int kk = 0; kk < 2; ++kk) {
        bf16x8 af = *(const bf16x8*)&Wt[w][l15 * 64 + ((kk * 32 + l4 * 8) ^ (sw << 3))];
#pragma unroll
        for (int n = 0; n < 8; ++n) {
          bf16x8 bf = *(const bf16x8*)&Vc[(n * 16 + l15) * 64 + (((kk * 4 + l4) ^ sw) << 3)];
          o[n] = MFMA_B16(af, bf, o[n]);
        }
      }
      __syncthreads();
    }
    float invd[4];
#pragma unroll
    for (int r = 0; r < 4; ++r) {
      float d = dens[r];
      d += __shfl_xor(d, 1);
      d += __shfl_xor(d, 2);
      d += __shfl_xor(d, 4);
      d += __shfl_xor(d, 8);
      invd[r] = 1.0f / fmaxf(d, 1e-30f);
    }
#pragma unroll
    for (int n = 0; n < 8; ++n)
#pragma unroll
      for (int r = 0; r < 4; ++r) {
        size_t row = qb * 64 + w * 16 + l4 * 4 + r;
        size_t col = h * HD + n * 16 + l15;
        ctx[row * HID + col] = (_Float16)(o[n][r] * invd[r]);
      }
  }
}

// ---------------- host glue ----------------
extern "C" void kernel_launch(void* const* d_in, const int* in_sizes, int n_in,
                              void* d_out, int out_size, void* d_ws, size_t ws_size,
                              hipStream_t stream) {
  const float* hidden = (const float*)d_in[0];
  const float* cosb = (const float*)d_in[2];
  const float* sinb = (const float*)d_in[3];
  const float* q_w = (const float*)d_in[4];
  const float* q_b = (const float*)d_in[5];
  const float* k_w = (const float*)d_in[6];
  const float* k_b = (const float*)d_in[7];
  const float* v_w = (const float*)d_in[8];
  const float* v_b = (const float*)d_in[9];
  const float* o_w = (const float*)d_in[10];

  char* ws = (char*)d_ws;
  // Phase A (QKV GEMM):
  float* qkv_f32 = (float*)(ws + 0);                        // 37,748,736
  _Float16* hf16 = (_Float16*)(ws + 37748736);              // 14,680,064 -> 52,428,800
  _Float16* wqkv16 = (_Float16*)(ws + 52428800);            // 33,030,144 -> 85,458,944
  float* biasb = (float*)(ws + 85458944);                   //     18,432 -> 85,477,376
  // Phase B overlays:
  _Float16* q16 = (_Float16*)(ws + 37748736);               // 14,680,064 (over dead hf16)
  _Float16* wo16 = (_Float16*)(ws + 52428800);              // 25,690,112 (over dead wqkv16)
  _Float16* k16 = (_Float16*)(ws + 85477376);               //  2,097,152 -> 87,574,528
  __hip_bfloat16* vt = (__hip_bfloat16*)(ws + 87574528);    //  2,097,152 -> 89,671,680
  float* scores = (float*)(ws + 89671680);                  //    229,376 -> 89,901,056
  unsigned char* keep = (unsigned char*)(ws + 89901056);    //     57,344 -> 89,958,400
  int* ctrs = (int*)(ws + 89958400);                        //          8 -> 89,958,408 peak
  // Phase C overlay (qkv_f32 dead after rope+vtrans):
  _Float16* ctx16 = (_Float16*)(ws + 0);                    // 14,680,064

  hipMemcpyAsync(biasb, q_b, 3584 * 4, hipMemcpyDeviceToDevice, stream);
  hipMemcpyAsync(biasb + 3584, k_b, 512 * 4, hipMemcpyDeviceToDevice, stream);
  hipMemcpyAsync(biasb + 4096, v_b, 512 * 4, hipMemcpyDeviceToDevice, stream);

  // fp16 operand conversion
  cvt_f32_f16<<<7168, 256, 0, stream>>>(hidden, hf16, 1835008);
  cvt_f32_f16<<<12544, 256, 0, stream>>>(q_w, wqkv16, 3211264);
  cvt_f32_f16<<<1792, 256, 0, stream>>>(k_w, wqkv16 + (size_t)3584 * 3584, 458752);
  cvt_f32_f16<<<1792, 256, 0, stream>>>(v_w, wqkv16 + (size_t)4096 * 3584, 458752);

  // QKV projection (fp16 MFMA, fp32 accum, +bias)
  gemm_f16<true><<<dim3(36, 16), 256, 0, stream>>>(hf16, HID, wqkv16, HID,
                                                   biasb, qkv_f32, QKV_N, HID);

  // o_w conversion into now-dead wqkv space (stream-ordered)
  cvt_f32_f16<<<12544, 256, 0, stream>>>(o_w, wo16, 3211264);

  rope_f16<<<16384, 256, 0, stream>>>(qkv_f32, cosb, sinb, q16, k16);
  vtrans<<<dim3(32, 2, 4), 256, 0, stream>>>(qkv_f32, vt);
  hipMemsetAsync(scores, 0, NHEADS * S_LEN * 4, stream);
  hipMemsetAsync(ctrs, 0, 8, stream);

  attn_ls<<<512, 256, 0, stream>>>(q16, k16, scores, &ctrs[0]);
  h2o_topk<<<28, 256, 0, stream>>>(scores, keep);
  attn_out<<<512, 256, 0, stream>>>(q16, k16, vt, keep, ctx16, &ctrs[1]);

  // output projection (fp16 MFMA, fp32 accum)
  gemm_f16<false><<<dim3(28, 16), 256, 0, stream>>>(ctx16, HID, wo16, HID,
                                                    nullptr, (float*)d_out, HID, HID);
}